// Round 14
// baseline (264.137 us; speedup 1.0000x reference)
//
#include <hip/hip_runtime.h>
#include <cstdint>
#include <cstddef>

#define NHEADS 16
#define HDIM   128
#define BATCH  2
#define SEQ    2048
#define DMODEL 2048
#define MTOT   (BATCH*SEQ)     // 4096
#define NQKV   (3*DMODEL)      // 6144

typedef __attribute__((ext_vector_type(8))) __bf16 bf16x8;
typedef __attribute__((ext_vector_type(4))) float f32x4;
typedef __attribute__((ext_vector_type(8))) unsigned short ushort8v;

__device__ __forceinline__ unsigned short f2bf(float f){
  __bf16 h = (__bf16)f;
  return __builtin_bit_cast(unsigned short, h);
}
__device__ __forceinline__ float bf2f(unsigned short s){
  return __uint_as_float(((uint32_t)s) << 16);
}
// async global->LDS, 16B per lane; LDS dest is wave-uniform base (+lane*16 by HW)
__device__ __forceinline__ void gload_lds16(const void* src, void* lds_base){
  __builtin_amdgcn_global_load_lds((const __attribute__((address_space(1))) unsigned int*)src,
                                   (__attribute__((address_space(3))) unsigned int*)lds_base,
                                   16, 0, 0);
}

// DPP 16-lane-row rotation butterflies (see round 2)
template<int CTRL>
__device__ __forceinline__ float dppmv(float x){
  return __uint_as_float((unsigned)__builtin_amdgcn_update_dpp(
      0, (int)__float_as_uint(x), CTRL, 0xF, 0xF, true));
}
__device__ __forceinline__ float rmax16(float x){
  x = fmaxf(x, dppmv<0x128>(x));
  x = fmaxf(x, dppmv<0x124>(x));
  x = fmaxf(x, dppmv<0x122>(x));
  x = fmaxf(x, dppmv<0x121>(x));
  return x;
}
__device__ __forceinline__ float rsum16(float x){
  x += dppmv<0x128>(x);
  x += dppmv<0x124>(x);
  x += dppmv<0x122>(x);
  x += dppmv<0x121>(x);
  return x;
}

// ------ fused cast fp32 -> bf16 (3 arrays) + rope cos/sin table build ------
__global__ void cast3_kernel(const float* __restrict__ s0, unsigned short* __restrict__ d0, int n0,
                             const float* __restrict__ s1, unsigned short* __restrict__ d1, int n1,
                             const float* __restrict__ s2, unsigned short* __restrict__ d2, int n2,
                             float2* __restrict__ tab){
  {
    const int i = blockIdx.x*blockDim.x + threadIdx.x;
    if (i < SEQ*64){
      const int j = i & 63, s = i >> 6;
      const float inv = exp2f(-(float)j * (13.287712379549449f/64.f));
      float sn, cs;
      sincosf((float)s * inv, &sn, &cs);
      tab[i] = make_float2(cs, sn);
    }
  }
  const int stride = gridDim.x*blockDim.x*8;
  const int base = (blockIdx.x*blockDim.x + threadIdx.x)*8;
  #pragma unroll 1
  for (int a = 0; a < 3; ++a){
    const float* s = a==0 ? s0 : (a==1 ? s1 : s2);
    unsigned short* d = a==0 ? d0 : (a==1 ? d1 : d2);
    const int n = a==0 ? n0 : (a==1 ? n1 : n2);
    for (int i = base; i < n; i += stride){
      float4 x = *reinterpret_cast<const float4*>(s + i);
      float4 y = *reinterpret_cast<const float4*>(s + i + 4);
      ushort8v o;
      o[0]=f2bf(x.x); o[1]=f2bf(x.y); o[2]=f2bf(x.z); o[3]=f2bf(x.w);
      o[4]=f2bf(y.x); o[5]=f2bf(y.y); o[6]=f2bf(y.z); o[7]=f2bf(y.w);
      *reinterpret_cast<ushort8v*>(d + i) = o;
    }
  }
}

// ---------- 128x256 B^T GEMM, BK=32, single-phase, 2 blocks/CU (QKV) -------
// r14: BK 64->32 cuts staging LDS to 48KB (69.6KB with epilogue scratch) ->
// 2 blocks/CU, 16 waves/CU: m97-style implicit cross-block overlap hides the
// per-tile vmcnt(0) drain (m97 measured 874-912 TF with this mechanism).
// Per tile: {issue 3 stages->nxt | 8 frag reads | lgkm(0) | 16 MFMA |
// vmcnt(0) | barrier}. Swizzle for 64B rows: XOR key (r>>1)&3 -> 8 bank
// groups per 16 lanes = 2-way (free); (r&3) would be 4-way.
template<int MODE>
__global__ __launch_bounds__(512, 4) void gemm2(
    const unsigned short* __restrict__ A,
    const unsigned short* __restrict__ Bw,
    float* __restrict__ Cf,
    unsigned short* __restrict__ qo,
    unsigned short* __restrict__ ko,
    unsigned short* __restrict__ vo,
    const float2* __restrict__ rtab,
    int M, int N, int K)
{
  // staging view: [2][3][128*32] = 24576 ushorts; epilogue scratch needs
  // up to 256*136 = 34816 ushorts (69632 B <= 73728 -> 2 blocks/CU packs).
  __shared__ __align__(16) unsigned short smem[34816];
  auto lds = reinterpret_cast<unsigned short (*)[3][128*32]>(smem);
  // slots: 0=A[128x32]  1=B0 (n 0..127)  2=B1 (n 128..255)

  const int lane = threadIdx.x & 63;
  const int wid  = threadIdx.x >> 6;
  const int wm = wid >> 2, wn = wid & 3;     // 2M x 4N, per-wave 64x64
  const int hi = lane >> 4;
  const int l15 = lane & 15;

  const int nwg = gridDim.x * gridDim.y;
  const int bid = blockIdx.y * gridDim.x + blockIdx.x;
  const int swz = (bid & 7) * (nwg >> 3) + (bid >> 3);
  const int by = swz & 31;
  const int bx = swz >> 5;
  const int m0 = by * 128;
  const int n0 = bx * 256;

  const int NT = K >> 5;

  // one gload/thread covers a full 8KB slot (512 thr x 16B)
  auto stage = [&](const unsigned short* base, int row0, int k0, int buf, int slot){
    const int r = threadIdx.x >> 2;                    // 0..127
    const int csrc = (((threadIdx.x & 3) ^ ((r>>1)&3)) << 3);
    gload_lds16(base + (size_t)(row0 + r)*K + k0 + csrc,
                &lds[buf][slot][wid*512]);
  };
  auto frag = [&](const unsigned short* h, int r, int s){
    return *reinterpret_cast<const bf16x8*>(h + r*32 + ((s ^ ((r>>1)&3)) << 3));
  };

  f32x4 acc[4][4];
  #pragma unroll
  for (int i=0;i<4;++i)
    #pragma unroll
    for (int j=0;j<4;++j) acc[i][j] = (f32x4){0.f,0.f,0.f,0.f};

  stage(A,  m0,     0, 0, 0);
  stage(Bw, n0,     0, 0, 1);
  stage(Bw, n0+128, 0, 0, 2);
  asm volatile("s_waitcnt vmcnt(0)" ::: "memory");
  __builtin_amdgcn_sched_barrier(0);
  __builtin_amdgcn_s_barrier();

  bf16x8 Ar[4], Br[4];

  for (int kt = 0; kt < NT; ++kt){
    const int cur = kt & 1, nxt = cur ^ 1;
    const unsigned short* Ah = &lds[cur][0][0];
    const unsigned short* Bh = &lds[cur][1 + (wn>>1)][0];
    const int rbase = (wn & 1) * 64;

    if (kt+1 < NT){
      stage(A,  m0,     (kt+1)*32, nxt, 0);
      stage(Bw, n0,     (kt+1)*32, nxt, 1);
      stage(Bw, n0+128, (kt+1)*32, nxt, 2);
    }
    #pragma unroll
    for (int fm=0;fm<4;++fm) Ar[fm] = frag(Ah, wm*64 + fm*16 + l15, hi);
    #pragma unroll
    for (int p=0;p<4;++p)    Br[p]  = frag(Bh, rbase + p*16 + l15, hi);
    asm volatile("s_waitcnt lgkmcnt(0)" ::: "memory");
    __builtin_amdgcn_sched_barrier(0);
    __builtin_amdgcn_s_setprio(1);
    #pragma unroll
    for (int fm=0;fm<4;++fm)
      #pragma unroll
      for (int p=0;p<4;++p)
        acc[fm][p] = __builtin_amdgcn_mfma_f32_16x16x32_bf16(Ar[fm], Br[p], acc[fm][p], 0,0,0);
    __builtin_amdgcn_s_setprio(0);
    if (kt+1 < NT) asm volatile("s_waitcnt vmcnt(0)" ::: "memory");
    __builtin_amdgcn_sched_barrier(0);
    __builtin_amdgcn_s_barrier();
  }

  // ---- epilogue (unchanged from r13) ----
  if (MODE == 0 && (n0 >> 11) == 2){
    // V block: transpose 256(d) x 128(s) tile through LDS, coalesced vT store
    unsigned short* trsp = smem;                  // [256 d][136] ushorts
    #pragma unroll
    for (int fm=0;fm<4;++fm){
      const int srow = wm*64 + fm*16 + hi*4;
      #pragma unroll
      for (int p=0;p<4;++p){
        const int dcol = wn*64 + p*16 + l15;
        f32x4 v = acc[fm][p];
        ushort4 pk;
        pk.x=f2bf(v[0]); pk.y=f2bf(v[1]); pk.z=f2bf(v[2]); pk.w=f2bf(v[3]);
        *reinterpret_cast<ushort4*>(trsp + dcol*136 + srow) = pk;
      }
    }
    __syncthreads();
    const int bb  = m0 >> 11;
    const int ss0 = m0 & 2047;
    const size_t vrow = (size_t)(bb*2048 + (n0 - 4096));
    const int t = threadIdx.x;
    #pragma unroll
    for (int it=0; it<8; ++it){
      const int dl = it*32 + (t>>4);
      const int ch = t & 15;
      ushort8v val = *reinterpret_cast<const ushort8v*>(trsp + dl*136 + ch*8);
      *reinterpret_cast<ushort8v*>(vo + (vrow + dl)*SEQ + ss0 + ch*8) = val;
    }
  } else if (MODE == 0){
    // Q/K block: stage tile row-major in LDS, then fused rope (table) + store
    unsigned short* trsp = smem;                  // [128 rows][264] ushorts
    #pragma unroll
    for (int fm=0;fm<4;++fm){
      const int rowl = wm*64 + fm*16 + hi*4;
      #pragma unroll
      for (int p=0;p<4;++p){
        const int c = wn*64 + p*16 + l15;
        f32x4 v = acc[fm][p];
        #pragma unroll
        for (int r=0;r<4;++r) trsp[(rowl+r)*264 + c] = f2bf(v[r]);
      }
    }
    __syncthreads();
    const bool isq = (n0 >> 11) == 0;
    unsigned short* dst = isq ? qo : ko;
    const float QS = 0.08838834764831845f * 1.4426950408889634f;  // scale*log2e
    const int t = threadIdx.x;                    // 512 threads
    #pragma unroll
    for (int it=0; it<4; ++it){
      const int v = it*512 + t;
      const int rv = v >> 4;
      const int head = (v >> 3) & 1;
      const int jb = (v & 7) * 8;
      ushort8v a = *reinterpret_cast<const ushort8v*>(trsp + rv*264 + head*128 + jb);
      ushort8v b = *reinterpret_cast<const ushort8v*>(trsp + rv*264 + head*128 + 64 + jb);
      const int grow = m0 + rv;
      const int ss = grow & 2047, bb = grow >> 11;
      const int hh = ((n0 >> 7) & 15) + head;
      const float4* tb = reinterpret_cast<const float4*>(rtab + (size_t)ss*64 + jb);
      float csv[8], snv[8];
      #pragma unroll
      for (int q=0;q<4;++q){
        float4 tq = tb[q];
        csv[2*q]   = tq.x; snv[2*q]   = tq.y;
        csv[2*q+1] = tq.z; snv[2*q+1] = tq.w;
      }
      ushort8v o1, o2;
      #pragma unroll
      for (int e=0;e<8;++e){
        float x1 = bf2f(a[e]), x2 = bf2f(b[e]);
        float r1 = x1*csv[e] - x2*snv[e];
        float r2 = x2*csv[e] + x1*snv[e];
        if (isq){ r1 *= QS; r2 *= QS; }
        o1[e] = f2bf(r1); o2[e] = f2bf(r2);
      }
      unsigned short* base = dst + ((size_t)(bb*NHEADS+hh)*SEQ + ss)*HDIM;
      *reinterpret_cast<ushort8v*>(base + jb)      = o1;
      *reinterpret_cast<ushort8v*>(base + 64 + jb) = o2;
    }
  } else {
    #pragma unroll
    for (int fm=0;fm<4;++fm){
      const int row0 = m0 + wm*64 + fm*16 + (hi<<2);
      #pragma unroll
      for (int p=0;p<4;++p){
        const int col = n0 + wn*64 + p*16 + l15;
        f32x4 v = acc[fm][p];
        #pragma unroll
        for (int r=0;r<4;++r) Cf[(size_t)(row0+r)*N + col] = v[r];
      }
    }
  }
}

// ---------- 128x128 B^T GEMM, 4 waves, 64KB LDS -> 2 blocks/CU (out-proj) --
__global__ __launch_bounds__(256, 2) void gemm_op(
    const unsigned short* __restrict__ A,
    const unsigned short* __restrict__ Bw,
    float* __restrict__ Cf,
    int M, int N, int K)
{
  __shared__ __align__(16) unsigned short smem[2][2][128*64];   // 64 KB
  const int lane = threadIdx.x & 63;
  const int wid  = threadIdx.x >> 6;          // 0..3
  const int wm = wid >> 1, wn = wid & 1;      // 2M x 2N, per-wave 64x64
  const int hi = lane >> 4;
  const int l15 = lane & 15;

  const int nwg = gridDim.x * gridDim.y;      // 512
  const int bid = blockIdx.y * gridDim.x + blockIdx.x;
  const int swz = (bid & 7) * (nwg >> 3) + (bid >> 3);
  const int by = swz & 31;
  const int bx = swz >> 5;                    // 0..15
  const int m0 = by * 128;
  const int n0 = bx * 128;

  const int NT = K >> 6;

  auto stage = [&](const unsigned short* base, int row0, int k0, int buf, int slot){
    const int rlo = wid << 5;                 // 32 rows per wave
    #pragma unroll
    for (int i=0;i<4;++i){
      const int r = rlo + i*8 + (lane>>3);
      const int csrc = ((lane&7) ^ (lane>>3)) << 3;
      gload_lds16(base + (size_t)(row0 + r)*K + k0 + csrc,
                  &smem[buf][slot][(rlo + i*8)*64]);
    }
  };
  auto frag = [&](const unsigned short* h, int r, int s){
    return *reinterpret_cast<const bf16x8*>(h + r*64 + ((s ^ (r&7)) << 3));
  };

  f32x4 acc[4][4];
  #pragma unroll
  for (int i=0;i<4;++i)
    #pragma unroll
    for (int j=0;j<4;++j) acc[i][j] = (f32x4){0.f,0.f,0.f,0.f};

  // prologue: t0 {A,B} + t1 {A}; vmcnt(4) => t0 landed, A(t1) in flight
  stage(A,  m0, 0, 0, 0);
  stage(Bw, n0, 0, 0, 1);
  if (NT > 1){
    stage(A, m0, 64, 1, 0);
    asm volatile("s_waitcnt vmcnt(4)" ::: "memory");
  } else {
    asm volatile("s_waitcnt vmcnt(0)" ::: "memory");
  }
  __builtin_amdgcn_sched_barrier(0);
  __builtin_amdgcn_s_barrier();

  bf16x8 Ar[4][2];
  bf16x8 Br[2][2];

  auto tile_body = [&](int kt, int cur){
    const int nxt = cur ^ 1;
    const unsigned short* Ah = &smem[cur][0][0];
    const unsigned short* Bh = &smem[cur][1][0];
    const int rbase = wn * 64;

    // ===== P0: A(8) + B-lo(4) reads; stage t+1.B -> nxt =====
    #pragma unroll
    for (int fm=0;fm<4;++fm)
      #pragma unroll
      for (int kk=0;kk<2;++kk)
        Ar[fm][kk] = frag(Ah, wm*64 + fm*16 + l15, kk*4 + hi);
    #pragma unroll
    for (int nf=0;nf<2;++nf)
      #pragma unroll
      for (int kk=0;kk<2;++kk)
        Br[nf][kk] = frag(Bh, rbase + nf*16 + l15, kk*4 + hi);
    if (kt+1 < NT) stage(Bw, n0, (kt+1)*64, nxt, 1);
    asm volatile("s_waitcnt lgkmcnt(8)" ::: "memory");
    __builtin_amdgcn_sched_barrier(0);
    __builtin_amdgcn_s_barrier();
    asm volatile("s_waitcnt lgkmcnt(0)" ::: "memory");
    __builtin_amdgcn_sched_barrier(0);
    __builtin_amdgcn_s_setprio(1);
    #pragma unroll
    for (int fm=0;fm<4;++fm){
      acc[fm][0] = __builtin_amdgcn_mfma_f32_16x16x32_bf16(Ar[fm][0], Br[0][0], acc[fm][0], 0,0,0);
      acc[fm][0] = __builtin_amdgcn_mfma_f32_16x16x32_bf16(Ar[fm][1], Br[0][1], acc[fm][0], 0,0,0);
      acc[fm][1] = __builtin_amdgcn_mfma_f32_16x16x32_bf16(Ar[fm][0], Br[1][0], acc[fm][1], 0,0,0);
      acc[fm][1] = __builtin_amdgcn_mfma_f32_16x16x32_bf16(Ar[fm][1], Br[1][1], acc[fm][1], 0,0,0);
    }
    __builtin_amdgcn_s_setprio(0);
    __builtin_amdgcn_sched_barrier(0);
    __builtin_amdgcn_s_barrier();

    // ===== P1: B-hi(4) reads; stage t+2.A -> cur; vmcnt(4) =====
    #pragma unroll
    for (int nf=0;nf<2;++nf)
      #pragma unroll
      for (int kk=0;kk<2;++kk)
        Br[nf][kk] = frag(Bh, rbase + 32 + nf*16 + l15, kk*4 + hi);
    if (kt+2 < NT) stage(A, m0, (kt+2)*64, cur, 0);
    __builtin_amdgcn_sched_barrier(0);
    __builtin_amdgcn_s_barrier();
    asm volatile("s_waitcnt lgkmcnt(0)" ::: "memory");
    __builtin_amdgcn_sched_barrier(0);
    __builtin_amdgcn_s_setprio(1);
    #pragma unroll
    for (int fm=0;fm<4;++fm){
      acc[fm][2] = __builtin_amdgcn_mfma_f32_16x16x32_bf16(Ar[fm][0], Br[0][0], acc[fm][2], 0,0,0);
      acc[fm][2] = __builtin_amdgcn_mfma_f32_16x16x32_bf16(Ar[fm][1], Br[0][1], acc[fm][2], 0,0,0);
      acc[fm][3] = __builtin_amdgcn_mfma_f32_16x16x32_bf16(Ar[fm][0], Br[1][0], acc[fm][3], 0,0,0);
      acc[fm][3] = __builtin_amdgcn_mfma_f32_16x16x32_bf16(Ar[fm][1], Br[1][1], acc[fm][3], 0,0,0);
    }
    __builtin_amdgcn_s_setprio(0);
    if (kt+2 < NT)      asm volatile("s_waitcnt vmcnt(4)" ::: "memory");
    else if (kt+1 < NT) asm volatile("s_waitcnt vmcnt(0)" ::: "memory");
    __builtin_amdgcn_sched_barrier(0);
    __builtin_amdgcn_s_barrier();
  };

  for (int kt2 = 0; kt2 < NT; kt2 += 2){
    tile_body(kt2,     0);
    tile_body(kt2 + 1, 1);
  }

  #pragma unroll
  for (int fm=0;fm<4;++fm){
    const int row0 = m0 + wm*64 + fm*16 + (hi<<2);
    #pragma unroll
    for (int p=0;p<4;++p){
      const int col = n0 + wn*64 + p*16 + l15;
      f32x4 v = acc[fm][p];
      #pragma unroll
      for (int r=0;r<4;++r) Cf[(size_t)(row0+r)*N + col] = v[r];
    }
  }
}

// ---------------- causal flash attention (v6: shared-vb PV) ----------------
// r14: PV hoisted out of the per-frag loop; pa held in regs for both frags;
// vb read ONCE feeding both frags' MFMAs on co-active tiles (kt<=pr).
__global__ __launch_bounds__(256, 2) void attn_kernel(
    const unsigned short* __restrict__ qh,
    const unsigned short* __restrict__ kh,
    const unsigned short* __restrict__ vT,
    unsigned short* __restrict__ ao)
{
  __shared__ __align__(16) unsigned short Ks[2][64*128];   // 32 KB
  __shared__ __align__(16) unsigned short Vs[2][128*64];   // 32 KB
  __shared__ __align__(16) unsigned short Ps[4][16*64];    //  8 KB -> 72 KB

  const int lane = threadIdx.x & 63;
  const int wid  = threadIdx.x >> 6;
  const int hi   = lane >> 4;
  const int l15  = lane & 15;
  const int pr = blockIdx.x;          // pair index 0..15
  const int bh = blockIdx.y;
  const int b_ = bh >> 4, h_ = bh & 15;

  const unsigned short* Qb = qh + (size_t)bh * SEQ * HDIM;
  const unsigned short* Kb = kh + (size_t)bh * SEQ * HDIM;
  const unsigned short* Vb = vT + (size_t)bh * HDIM * SEQ;

  const int qrowf[2] = { pr*64 + wid*16, (31-pr)*64 + wid*16 };

  auto stageKV = [&](int kg, int buf){
    #pragma unroll
    for (int i=0;i<4;++i){
      const int r  = (wid*4+i)*4 + (lane>>4);
      const int cb = ((lane&15)<<4) ^ ((r&7)<<4);
      gload_lds16(Kb + (size_t)(kg*64 + r)*HDIM + (cb>>1), &Ks[buf][0] + (wid*4+i)*512);
    }
    #pragma unroll
    for (int i=0;i<4;++i){
      const int d  = (wid*4+i)*8 + (lane>>3);
      const int cb = ((lane&7)<<4) ^ ((d&7)<<4);
      gload_lds16(Vb + (size_t)d*SEQ + kg*64 + (cb>>1), &Vs[buf][0] + (wid*4+i)*512);
    }
  };

  bf16x8 qf[2][4];
  #pragma unroll
  for (int fi=0; fi<2; ++fi){
    const int qr = qrowf[fi] + l15;
    #pragma unroll
    for (int ks = 0; ks < 4; ++ks)
      qf[fi][ks] = *reinterpret_cast<const bf16x8*>(Qb + (size_t)qr*HDIM + ks*32 + hi*8);
  }

  f32x4 oacc[2][8];
  #pragma unroll
  for (int fi=0;fi<2;++fi)
    #pragma unroll
    for (int t=0;t<8;++t) oacc[fi][t] = (f32x4){0.f,0.f,0.f,0.f};
  float mrun[2][4], lrun[2][4];
  #pragma unroll
  for (int fi=0;fi<2;++fi)
    #pragma unroll
    for (int r=0;r<4;++r){ mrun[fi][r] = -3.0e38f; lrun[fi][r] = 0.f; }

  const int nkt = 32 - pr;            // union of KV ranges for both frags

  stageKV(0, 0);
  __syncthreads();

  for (int kt = 0; kt < nkt; ++kt){
    const int cur = kt & 1;
    if (kt + 1 < nkt) stageKV(kt + 1, cur ^ 1);

    const bool lo_act = (kt <= pr);   // frag 0 active; frag 1 always active

    // ---- S = Q K^T (kf shared across active frags) ----
    f32x4 sacc[2][4];
    #pragma unroll
    for (int fi=0;fi<2;++fi)
      #pragma unroll
      for (int nt=0;nt<4;++nt) sacc[fi][nt] = (f32x4){0.f,0.f,0.f,0.f};
    __builtin_amdgcn_s_setprio(1);
    #pragma unroll
    for (int nt=0;nt<4;++nt){
      const int krow = nt*16 + l15;
      bf16x8 kf[4];
      #pragma unroll
      for (int ks=0;ks<4;++ks){
        const int cb = (ks*64 + (hi<<4)) ^ ((krow&7)<<4);
        kf[ks] = *reinterpret_cast<const bf16x8*>(&Ks[cur][0] + krow*128 + (cb>>1));
      }
      #pragma unroll
      for (int ks=0;ks<4;++ks)
        sacc[1][nt] = __builtin_amdgcn_mfma_f32_16x16x32_bf16(qf[1][ks], kf[ks], sacc[1][nt], 0,0,0);
      if (lo_act){
        #pragma unroll
        for (int ks=0;ks<4;++ks)
          sacc[0][nt] = __builtin_amdgcn_mfma_f32_16x16x32_bf16(qf[0][ks], kf[ks], sacc[0][nt], 0,0,0);
      }
    }
    __builtin_amdgcn_s_setprio(0);

    // ---- per-frag: mask, online softmax (defer-max), P write, pa read ----
    char* pb = (char*)&Ps[wid][0];
    bf16x8 pa[2][2];
    #pragma unroll
    for (int fi=0; fi<2; ++fi){
      if (fi == 0 && !lo_act) continue;

      if (kt*64 + 63 > qrowf[fi]){          // mask only on diagonal tiles
        #pragma unroll
        for (int nt=0;nt<4;++nt){
          const int key = kt*64 + nt*16 + l15;
          #pragma unroll
          for (int r=0;r<4;++r){
            const int qr = qrowf[fi] + hi*4 + r;
            if (key > qr) sacc[fi][nt][r] = -1.0e30f;
          }
        }
      }

      // defer-max (T13): skip rescale while max grows by <= 8 (log2 units)
      float mx[4]; float need = 0.f;
      #pragma unroll
      for (int r=0;r<4;++r){
        float m_ = fmaxf(fmaxf(sacc[fi][0][r], sacc[fi][1][r]),
                         fmaxf(sacc[fi][2][r], sacc[fi][3][r]));
        m_ = rmax16(m_);
        mx[r] = m_;
        need = fmaxf(need, m_ - mrun[fi][r]);
      }
      if (!__all(need <= 8.0f)){
        float fac[4];
        #pragma unroll
        for (int r=0;r<4;++r){
          const float mnew = fmaxf(mrun[fi][r], mx[r]);
          fac[r] = exp2f(mrun[fi][r] - mnew);
          mrun[fi][r] = mnew;
          lrun[fi][r] *= fac[r];
        }
        #pragma unroll
        for (int t=0;t<8;++t)
          #pragma unroll
          for (int r=0;r<4;++r) oacc[fi][t][r] *= fac[r];
      }
      #pragma unroll
      for (int r=0;r<4;++r){
        float ps = 0.f;
        #pragma unroll
        for (int nt=0;nt<4;++nt){
          const float p = exp2f(sacc[fi][nt][r] - mrun[fi][r]);
          sacc[fi][nt][r] = p;
          ps += p;
        }
        ps = rsum16(ps);
        lrun[fi][r] += ps;
      }

      // P (bf16) -> per-wave LDS (16 rows), swizzled
      #pragma unroll
      for (int nt=0;nt<4;++nt){
        const int keyb = (nt*16 + l15) << 1;
        #pragma unroll
        for (int r=0;r<4;++r){
          const int prow = hi*4 + r;
          *(unsigned short*)(pb + prow*128 + (keyb ^ ((prow&7)<<4))) = f2bf(sacc[fi][nt][r]);
        }
      }
      // wave-local LDS RAW: drain ds_writes before pa reads (rule #18)
      asm volatile("s_waitcnt lgkmcnt(0)" ::: "memory");
      __builtin_amdgcn_sched_barrier(0);

      {
        const int prow = l15;
        #pragma unroll
        for (int ks=0;ks<2;++ks){
          const int pcb = (ks*64 + (hi<<4)) ^ ((prow&7)<<4);
          pa[fi][ks] = *reinterpret_cast<const bf16x8*>(pb + prow*128 + pcb);
        }
      }
      // pa must land before next frag overwrites Ps (WAR, rule #18)
      asm volatile("s_waitcnt lgkmcnt(0)" ::: "memory");
      __builtin_amdgcn_sched_barrier(0);
    }

    // ---- O += P @ V : single cluster, vb shared across active frags ----
    __builtin_amdgcn_s_setprio(1);
    #pragma unroll
    for (int ks=0;ks<2;++ks){
      #pragma unroll
      for (int t=0;t<8;++t){
        const int drow = t*16 + l15;
        const int vcb = (ks*64 + (hi<<4)) ^ ((drow&7)<<4);
        bf16x8 vb = *reinterpret_cast<const bf16x8*>(&Vs[cur][0] + drow*64 + (vcb>>1));
        oacc[1][t] = __builtin_amdgcn_mfma_f32_16x16x32_bf16(pa[1][ks], vb, oacc[1][t], 0,0,0);
        if (lo_act)
          oacc[0][t] = __builtin_amdgcn_mfma_f32_16x16x32_bf16(pa[0][ks], vb, oacc[0][t], 0,0,0);
      }
    }
    __builtin_amdgcn_s_setprio(0);

    __syncthreads();   // drains next-tile vmcnt + protects K/V buffers
  }

  // ---- epilogue: both frags ----
  #pragma unroll
  for (int fi=0;fi<2;++fi){
    float linv[4];
    #pragma unroll
    for (int r=0;r<4;++r) linv[r] = 1.0f / lrun[fi][r];
    #pragma unroll
    for (int t=0;t<8;++t){
      const int col = h_*HDIM + t*16 + l15;
      #pragma unroll
      for (int r=0;r<4;++r){
        const int s_ = qrowf[fi] + hi*4 + r;
        ao[(size_t)(b_*SEQ + s_)*DMODEL + col] = f2bf(oacc[fi][t][r] * linv[r]);
      }
    }
  }
}

// ---------------- launch ----------------
extern "C" void kernel_launch(void* const* d_in, const int* in_sizes, int n_in,
                              void* d_out, int out_size, void* d_ws, size_t ws_size,
                              hipStream_t stream)
{
  const float* x     = (const float*)d_in[0];
  const float* w_qkv = (const float*)d_in[1];
  const float* w_out = (const float*)d_in[2];
  float* out = (float*)d_out;

  unsigned short* xb    = (unsigned short*)d_ws;                 // 4096x2048
  unsigned short* wqkvb = xb    + (size_t)MTOT*DMODEL;           // 6144x2048
  unsigned short* woutb = wqkvb + (size_t)NQKV*DMODEL;           // 2048x2048
  unsigned short* qhb   = woutb + (size_t)DMODEL*DMODEL;         // (B,H,S,D)
  unsigned short* khb   = qhb   + (size_t)MTOT*DMODEL;           // (B,H,S,D)
  unsigned short* vtb   = khb   + (size_t)MTOT*DMODEL;           // (B,H,D,S)
  unsigned short* aob   = vtb   + (size_t)MTOT*DMODEL;           // 4096x2048
  float2* rtab          = (float2*)(aob + (size_t)MTOT*DMODEL);  // 2048x64 (1 MB)

  hipLaunchKernelGGL(cast3_kernel, dim3(1024), dim3(256), 0, stream,
                     x, xb, MTOT*DMODEL, w_qkv, wqkvb, NQKV*DMODEL, w_out, woutb, DMODEL*DMODEL,
                     rtab);
  hipLaunchKernelGGL((gemm2<0>), dim3(NQKV/256, MTOT/128), dim3(512), 0, stream,
                     xb, wqkvb, (float*)nullptr, qhb, khb, vtb, rtab, MTOT, NQKV, DMODEL);
  hipLaunchKernelGGL(attn_kernel, dim3(16, BATCH*NHEADS), dim3(256), 0, stream, qhb, khb, vtb, aob);
  hipLaunchKernelGGL(gemm_op, dim3(DMODEL/128, MTOT/128), dim3(256), 0, stream,
                     aob, woutb, out, MTOT, DMODEL, DMODEL);
}

// Round 15
// 250.289 us; speedup vs baseline: 1.0553x; 1.0553x over previous
//
#include <hip/hip_runtime.h>
#include <cstdint>
#include <cstddef>

#define NHEADS 16
#define HDIM   128
#define BATCH  2
#define SEQ    2048
#define DMODEL 2048
#define MTOT   (BATCH*SEQ)     // 4096
#define NQKV   (3*DMODEL)      // 6144

typedef __attribute__((ext_vector_type(8))) __bf16 bf16x8;
typedef __attribute__((ext_vector_type(4))) float f32x4;
typedef __attribute__((ext_vector_type(8))) unsigned short ushort8v;

__device__ __forceinline__ unsigned short f2bf(float f){
  __bf16 h = (__bf16)f;
  return __builtin_bit_cast(unsigned short, h);
}
__device__ __forceinline__ float bf2f(unsigned short s){
  return __uint_as_float(((uint32_t)s) << 16);
}
// async global->LDS, 16B per lane; LDS dest is wave-uniform base (+lane*16 by HW)
__device__ __forceinline__ void gload_lds16(const void* src, void* lds_base){
  __builtin_amdgcn_global_load_lds((const __attribute__((address_space(1))) unsigned int*)src,
                                   (__attribute__((address_space(3))) unsigned int*)lds_base,
                                   16, 0, 0);
}

// DPP 16-lane-row rotation butterflies (see round 2)
template<int CTRL>
__device__ __forceinline__ float dppmv(float x){
  return __uint_as_float((unsigned)__builtin_amdgcn_update_dpp(
      0, (int)__float_as_uint(x), CTRL, 0xF, 0xF, true));
}
__device__ __forceinline__ float rmax16(float x){
  x = fmaxf(x, dppmv<0x128>(x));
  x = fmaxf(x, dppmv<0x124>(x));
  x = fmaxf(x, dppmv<0x122>(x));
  x = fmaxf(x, dppmv<0x121>(x));
  return x;
}
__device__ __forceinline__ float rsum16(float x){
  x += dppmv<0x128>(x);
  x += dppmv<0x124>(x);
  x += dppmv<0x122>(x);
  x += dppmv<0x121>(x);
  return x;
}

// ------ fused cast fp32 -> bf16 (3 arrays) + rope cos/sin table build ------
// Table: tab[s*64+j] = (cos(s*inv_j), sin(s*inv_j)), 2048x64 float2 = 1 MB.
__global__ void cast3_kernel(const float* __restrict__ s0, unsigned short* __restrict__ d0, int n0,
                             const float* __restrict__ s1, unsigned short* __restrict__ d1, int n1,
                             const float* __restrict__ s2, unsigned short* __restrict__ d2, int n2,
                             float2* __restrict__ tab){
  {
    const int i = blockIdx.x*blockDim.x + threadIdx.x;
    if (i < SEQ*64){
      const int j = i & 63, s = i >> 6;
      const float inv = exp2f(-(float)j * (13.287712379549449f/64.f));
      float sn, cs;
      sincosf((float)s * inv, &sn, &cs);
      tab[i] = make_float2(cs, sn);
    }
  }
  const int stride = gridDim.x*blockDim.x*8;
  const int base = (blockIdx.x*blockDim.x + threadIdx.x)*8;
  #pragma unroll 1
  for (int a = 0; a < 3; ++a){
    const float* s = a==0 ? s0 : (a==1 ? s1 : s2);
    unsigned short* d = a==0 ? d0 : (a==1 ? d1 : d2);
    const int n = a==0 ? n0 : (a==1 ? n1 : n2);
    for (int i = base; i < n; i += stride){
      float4 x = *reinterpret_cast<const float4*>(s + i);
      float4 y = *reinterpret_cast<const float4*>(s + i + 4);
      ushort8v o;
      o[0]=f2bf(x.x); o[1]=f2bf(x.y); o[2]=f2bf(x.z); o[3]=f2bf(x.w);
      o[4]=f2bf(y.x); o[5]=f2bf(y.y); o[6]=f2bf(y.z); o[7]=f2bf(y.w);
      *reinterpret_cast<ushort8v*>(d + i) = o;
    }
  }
}

// ---------- 128x256 B^T GEMM, BK=64, 2-phase counted-vmcnt (QKV) -----------
// MODE 0 epilogues: V blocks -> LDS transpose + coalesced vT store;
// Q/K blocks -> LDS roundtrip + FUSED ROPE via (cos,sin) TABLE + head store.
// (r14 lesson: BK=32 @2blk/CU neutral -> per-CU LDS-BW-bound; keep BK=64.)
template<int MODE>
__global__ __launch_bounds__(512, 2) void gemm2(
    const unsigned short* __restrict__ A,
    const unsigned short* __restrict__ Bw,
    float* __restrict__ Cf,
    unsigned short* __restrict__ qo,
    unsigned short* __restrict__ ko,
    unsigned short* __restrict__ vo,
    const float2* __restrict__ rtab,
    int M, int N, int K)
{
  __shared__ __align__(16) unsigned short smem[49152];
  auto lds = reinterpret_cast<unsigned short (*)[3][128*64]>(smem);  // [2][3][8192]

  const int lane = threadIdx.x & 63;
  const int wid  = threadIdx.x >> 6;
  const int wm = wid >> 2, wn = wid & 3;
  const int hi = lane >> 4;
  const int l15 = lane & 15;

  const int nwg = gridDim.x * gridDim.y;
  const int bid = blockIdx.y * gridDim.x + blockIdx.x;
  const int swz = (bid & 7) * (nwg >> 3) + (bid >> 3);
  const int by = swz & 31;
  const int bx = swz >> 5;
  const int m0 = by * 128;
  const int n0 = bx * 256;

  const int NT = K >> 6;

  auto stage = [&](const unsigned short* base, int row0, int k0, int buf, int slot){
    const int rlo = wid << 4;
    #pragma unroll
    for (int i=0;i<2;++i){
      const int r = rlo + i*8 + (lane>>3);
      const int csrc = ((lane&7) ^ (lane>>3)) << 3;   // elems
      gload_lds16(base + (size_t)(row0 + r)*K + k0 + csrc,
                  &lds[buf][slot][(rlo + i*8)*64]);
    }
  };
  auto frag = [&](const unsigned short* h, int r, int s){
    return *reinterpret_cast<const bf16x8*>(h + r*64 + ((s ^ (r&7)) << 3));
  };

  f32x4 acc[4][4];
  #pragma unroll
  for (int i=0;i<4;++i)
    #pragma unroll
    for (int j=0;j<4;++j) acc[i][j] = (f32x4){0.f,0.f,0.f,0.f};

  stage(A,  m0,      0, 0, 0);
  stage(Bw, n0,      0, 0, 1);
  stage(Bw, n0+128,  0, 0, 2);
  if (NT > 1){
    stage(A, m0, 64, 1, 0);
    asm volatile("s_waitcnt vmcnt(2)" ::: "memory");
  } else {
    asm volatile("s_waitcnt vmcnt(0)" ::: "memory");
  }
  __builtin_amdgcn_sched_barrier(0);
  __builtin_amdgcn_s_barrier();

  bf16x8 Ar[4][2];
  bf16x8 Br[2][2];

  auto tile_body = [&](int kt, int cur){
    const int nxt = cur ^ 1;
    const unsigned short* Ah = &lds[cur][0][0];
    const unsigned short* Bh = &lds[cur][1 + (wn>>1)][0];
    const int rbase = (wn & 1) * 64;

    // ===== P0 =====
    #pragma unroll
    for (int fm=0;fm<4;++fm)
      #pragma unroll
      for (int kk=0;kk<2;++kk)
        Ar[fm][kk] = frag(Ah, wm*64 + fm*16 + l15, kk*4 + hi);
    #pragma unroll
    for (int nf=0;nf<2;++nf)
      #pragma unroll
      for (int kk=0;kk<2;++kk)
        Br[nf][kk] = frag(Bh, rbase + nf*16 + l15, kk*4 + hi);
    if (kt+1 < NT){
      stage(Bw, n0,     (kt+1)*64, nxt, 1);
      stage(Bw, n0+128, (kt+1)*64, nxt, 2);
    }
    asm volatile("s_waitcnt lgkmcnt(8)" ::: "memory");
    __builtin_amdgcn_sched_barrier(0);
    __builtin_amdgcn_s_barrier();
    asm volatile("s_waitcnt lgkmcnt(0)" ::: "memory");
    __builtin_amdgcn_sched_barrier(0);
    __builtin_amdgcn_s_setprio(1);
    #pragma unroll
    for (int fm=0;fm<4;++fm){
      acc[fm][0] = __builtin_amdgcn_mfma_f32_16x16x32_bf16(Ar[fm][0], Br[0][0], acc[fm][0], 0,0,0);
      acc[fm][0] = __builtin_amdgcn_mfma_f32_16x16x32_bf16(Ar[fm][1], Br[0][1], acc[fm][0], 0,0,0);
      acc[fm][1] = __builtin_amdgcn_mfma_f32_16x16x32_bf16(Ar[fm][0], Br[1][0], acc[fm][1], 0,0,0);
      acc[fm][1] = __builtin_amdgcn_mfma_f32_16x16x32_bf16(Ar[fm][1], Br[1][1], acc[fm][1], 0,0,0);
    }
    __builtin_amdgcn_s_setprio(0);
    __builtin_amdgcn_sched_barrier(0);
    __builtin_amdgcn_s_barrier();

    // ===== P1 =====
    #pragma unroll
    for (int nf=0;nf<2;++nf)
      #pragma unroll
      for (int kk=0;kk<2;++kk)
        Br[nf][kk] = frag(Bh, rbase + 32 + nf*16 + l15, kk*4 + hi);
    if (kt+2 < NT) stage(A, m0, (kt+2)*64, cur, 0);
    __builtin_amdgcn_sched_barrier(0);
    __builtin_amdgcn_s_barrier();
    asm volatile("s_waitcnt lgkmcnt(0)" ::: "memory");
    __builtin_amdgcn_sched_barrier(0);
    __builtin_amdgcn_s_setprio(1);
    #pragma unroll
    for (int fm=0;fm<4;++fm){
      acc[fm][2] = __builtin_amdgcn_mfma_f32_16x16x32_bf16(Ar[fm][0], Br[0][0], acc[fm][2], 0,0,0);
      acc[fm][2] = __builtin_amdgcn_mfma_f32_16x16x32_bf16(Ar[fm][1], Br[0][1], acc[fm][2], 0,0,0);
      acc[fm][3] = __builtin_amdgcn_mfma_f32_16x16x32_bf16(Ar[fm][0], Br[1][0], acc[fm][3], 0,0,0);
      acc[fm][3] = __builtin_amdgcn_mfma_f32_16x16x32_bf16(Ar[fm][1], Br[1][1], acc[fm][3], 0,0,0);
    }
    __builtin_amdgcn_s_setprio(0);
    if (kt+2 < NT)      asm volatile("s_waitcnt vmcnt(2)" ::: "memory");
    else if (kt+1 < NT) asm volatile("s_waitcnt vmcnt(0)" ::: "memory");
    __builtin_amdgcn_sched_barrier(0);
    __builtin_amdgcn_s_barrier();
  };

  for (int kt2 = 0; kt2 < NT; kt2 += 2){
    tile_body(kt2,     0);
    tile_body(kt2 + 1, 1);
  }

  // ---- epilogue ----
  if (MODE == 0 && (n0 >> 11) == 2){
    // V block: transpose 256(d) x 128(s) tile through LDS, coalesced vT store
    unsigned short* trsp = smem;                  // [256 d][136] ushorts
    #pragma unroll
    for (int fm=0;fm<4;++fm){
      const int srow = wm*64 + fm*16 + hi*4;
      #pragma unroll
      for (int p=0;p<4;++p){
        const int dcol = wn*64 + p*16 + l15;
        f32x4 v = acc[fm][p];
        ushort4 pk;
        pk.x=f2bf(v[0]); pk.y=f2bf(v[1]); pk.z=f2bf(v[2]); pk.w=f2bf(v[3]);
        *reinterpret_cast<ushort4*>(trsp + dcol*136 + srow) = pk;
      }
    }
    __syncthreads();
    const int bb  = m0 >> 11;
    const int ss0 = m0 & 2047;
    const size_t vrow = (size_t)(bb*2048 + (n0 - 4096));
    const int t = threadIdx.x;
    #pragma unroll
    for (int it=0; it<8; ++it){
      const int dl = it*32 + (t>>4);
      const int ch = t & 15;
      ushort8v val = *reinterpret_cast<const ushort8v*>(trsp + dl*136 + ch*8);
      *reinterpret_cast<ushort8v*>(vo + (vrow + dl)*SEQ + ss0 + ch*8) = val;
    }
  } else if (MODE == 0){
    // Q/K block: stage tile row-major in LDS, then fused rope (table) + store
    unsigned short* trsp = smem;                  // [128 rows][264] ushorts
    #pragma unroll
    for (int fm=0;fm<4;++fm){
      const int rowl = wm*64 + fm*16 + hi*4;
      #pragma unroll
      for (int p=0;p<4;++p){
        const int c = wn*64 + p*16 + l15;
        f32x4 v = acc[fm][p];
        #pragma unroll
        for (int r=0;r<4;++r) trsp[(rowl+r)*264 + c] = f2bf(v[r]);
      }
    }
    __syncthreads();
    const bool isq = (n0 >> 11) == 0;
    unsigned short* dst = isq ? qo : ko;
    const float QS = 0.08838834764831845f * 1.4426950408889634f;  // scale*log2e
    const int t = threadIdx.x;                    // 512 threads
    #pragma unroll
    for (int it=0; it<4; ++it){
      const int v = it*512 + t;
      const int rv = v >> 4;
      const int head = (v >> 3) & 1;
      const int jb = (v & 7) * 8;
      ushort8v a = *reinterpret_cast<const ushort8v*>(trsp + rv*264 + head*128 + jb);
      ushort8v b = *reinterpret_cast<const ushort8v*>(trsp + rv*264 + head*128 + 64 + jb);
      const int grow = m0 + rv;
      const int ss = grow & 2047, bb = grow >> 11;
      const int hh = ((n0 >> 7) & 15) + head;
      const float4* tb = reinterpret_cast<const float4*>(rtab + (size_t)ss*64 + jb);
      float csv[8], snv[8];
      #pragma unroll
      for (int q=0;q<4;++q){
        float4 tq = tb[q];
        csv[2*q]   = tq.x; snv[2*q]   = tq.y;
        csv[2*q+1] = tq.z; snv[2*q+1] = tq.w;
      }
      ushort8v o1, o2;
      #pragma unroll
      for (int e=0;e<8;++e){
        float x1 = bf2f(a[e]), x2 = bf2f(b[e]);
        float r1 = x1*csv[e] - x2*snv[e];
        float r2 = x2*csv[e] + x1*snv[e];
        if (isq){ r1 *= QS; r2 *= QS; }
        o1[e] = f2bf(r1); o2[e] = f2bf(r2);
      }
      unsigned short* base = dst + ((size_t)(bb*NHEADS+hh)*SEQ + ss)*HDIM;
      *reinterpret_cast<ushort8v*>(base + jb)      = o1;
      *reinterpret_cast<ushort8v*>(base + 64 + jb) = o2;
    }
  } else {
    #pragma unroll
    for (int fm=0;fm<4;++fm){
      const int row0 = m0 + wm*64 + fm*16 + (hi<<2);
      #pragma unroll
      for (int p=0;p<4;++p){
        const int col = n0 + wn*64 + p*16 + l15;
        f32x4 v = acc[fm][p];
        #pragma unroll
        for (int r=0;r<4;++r) Cf[(size_t)(row0+r)*N + col] = v[r];
      }
    }
  }
}

// ---------- 128x128 B^T GEMM, 4 waves, 64KB LDS -> 2 blocks/CU (out-proj) --
__global__ __launch_bounds__(256, 2) void gemm_op(
    const unsigned short* __restrict__ A,
    const unsigned short* __restrict__ Bw,
    float* __restrict__ Cf,
    int M, int N, int K)
{
  __shared__ __align__(16) unsigned short smem[2][2][128*64];   // 64 KB
  const int lane = threadIdx.x & 63;
  const int wid  = threadIdx.x >> 6;          // 0..3
  const int wm = wid >> 1, wn = wid & 1;      // 2M x 2N, per-wave 64x64
  const int hi = lane >> 4;
  const int l15 = lane & 15;

  const int nwg = gridDim.x * gridDim.y;      // 512
  const int bid = blockIdx.y * gridDim.x + blockIdx.x;
  const int swz = (bid & 7) * (nwg >> 3) + (bid >> 3);
  const int by = swz & 31;
  const int bx = swz >> 5;                    // 0..15
  const int m0 = by * 128;
  const int n0 = bx * 128;

  const int NT = K >> 6;

  auto stage = [&](const unsigned short* base, int row0, int k0, int buf, int slot){
    const int rlo = wid << 5;                 // 32 rows per wave
    #pragma unroll
    for (int i=0;i<4;++i){
      const int r = rlo + i*8 + (lane>>3);
      const int csrc = ((lane&7) ^ (lane>>3)) << 3;
      gload_lds16(base + (size_t)(row0 + r)*K + k0 + csrc,
                  &smem[buf][slot][(rlo + i*8)*64]);
    }
  };
  auto frag = [&](const unsigned short* h, int r, int s){
    return *reinterpret_cast<const bf16x8*>(h + r*64 + ((s ^ (r&7)) << 3));
  };

  f32x4 acc[4][4];
  #pragma unroll
  for (int i=0;i<4;++i)
    #pragma unroll
    for (int j=0;j<4;++j) acc[i][j] = (f32x4){0.f,0.f,0.f,0.f};

  // prologue: t0 {A,B} + t1 {A}; vmcnt(4) => t0 landed, A(t1) in flight
  stage(A,  m0, 0, 0, 0);
  stage(Bw, n0, 0, 0, 1);
  if (NT > 1){
    stage(A, m0, 64, 1, 0);
    asm volatile("s_waitcnt vmcnt(4)" ::: "memory");
  } else {
    asm volatile("s_waitcnt vmcnt(0)" ::: "memory");
  }
  __builtin_amdgcn_sched_barrier(0);
  __builtin_amdgcn_s_barrier();

  bf16x8 Ar[4][2];
  bf16x8 Br[2][2];

  auto tile_body = [&](int kt, int cur){
    const int nxt = cur ^ 1;
    const unsigned short* Ah = &smem[cur][0][0];
    const unsigned short* Bh = &smem[cur][1][0];
    const int rbase = wn * 64;

    // ===== P0: A(8) + B-lo(4) reads; stage t+1.B -> nxt =====
    #pragma unroll
    for (int fm=0;fm<4;++fm)
      #pragma unroll
      for (int kk=0;kk<2;++kk)
        Ar[fm][kk] = frag(Ah, wm*64 + fm*16 + l15, kk*4 + hi);
    #pragma unroll
    for (int nf=0;nf<2;++nf)
      #pragma unroll
      for (int kk=0;kk<2;++kk)
        Br[nf][kk] = frag(Bh, rbase + nf*16 + l15, kk*4 + hi);
    if (kt+1 < NT) stage(Bw, n0, (kt+1)*64, nxt, 1);
    asm volatile("s_waitcnt lgkmcnt(8)" ::: "memory");
    __builtin_amdgcn_sched_barrier(0);
    __builtin_amdgcn_s_barrier();
    asm volatile("s_waitcnt lgkmcnt(0)" ::: "memory");
    __builtin_amdgcn_sched_barrier(0);
    __builtin_amdgcn_s_setprio(1);
    #pragma unroll
    for (int fm=0;fm<4;++fm){
      acc[fm][0] = __builtin_amdgcn_mfma_f32_16x16x32_bf16(Ar[fm][0], Br[0][0], acc[fm][0], 0,0,0);
      acc[fm][0] = __builtin_amdgcn_mfma_f32_16x16x32_bf16(Ar[fm][1], Br[0][1], acc[fm][0], 0,0,0);
      acc[fm][1] = __builtin_amdgcn_mfma_f32_16x16x32_bf16(Ar[fm][0], Br[1][0], acc[fm][1], 0,0,0);
      acc[fm][1] = __builtin_amdgcn_mfma_f32_16x16x32_bf16(Ar[fm][1], Br[1][1], acc[fm][1], 0,0,0);
    }
    __builtin_amdgcn_s_setprio(0);
    __builtin_amdgcn_sched_barrier(0);
    __builtin_amdgcn_s_barrier();

    // ===== P1: B-hi(4) reads; stage t+2.A -> cur; vmcnt(4) =====
    #pragma unroll
    for (int nf=0;nf<2;++nf)
      #pragma unroll
      for (int kk=0;kk<2;++kk)
        Br[nf][kk] = frag(Bh, rbase + 32 + nf*16 + l15, kk*4 + hi);
    if (kt+2 < NT) stage(A, m0, (kt+2)*64, cur, 0);
    __builtin_amdgcn_sched_barrier(0);
    __builtin_amdgcn_s_barrier();
    asm volatile("s_waitcnt lgkmcnt(0)" ::: "memory");
    __builtin_amdgcn_sched_barrier(0);
    __builtin_amdgcn_s_setprio(1);
    #pragma unroll
    for (int fm=0;fm<4;++fm){
      acc[fm][2] = __builtin_amdgcn_mfma_f32_16x16x32_bf16(Ar[fm][0], Br[0][0], acc[fm][2], 0,0,0);
      acc[fm][2] = __builtin_amdgcn_mfma_f32_16x16x32_bf16(Ar[fm][1], Br[0][1], acc[fm][2], 0,0,0);
      acc[fm][3] = __builtin_amdgcn_mfma_f32_16x16x32_bf16(Ar[fm][0], Br[1][0], acc[fm][3], 0,0,0);
      acc[fm][3] = __builtin_amdgcn_mfma_f32_16x16x32_bf16(Ar[fm][1], Br[1][1], acc[fm][3], 0,0,0);
    }
    __builtin_amdgcn_s_setprio(0);
    if (kt+2 < NT)      asm volatile("s_waitcnt vmcnt(4)" ::: "memory");
    else if (kt+1 < NT) asm volatile("s_waitcnt vmcnt(0)" ::: "memory");
    __builtin_amdgcn_sched_barrier(0);
    __builtin_amdgcn_s_barrier();
  };

  for (int kt2 = 0; kt2 < NT; kt2 += 2){
    tile_body(kt2,     0);
    tile_body(kt2 + 1, 1);
  }

  #pragma unroll
  for (int fm=0;fm<4;++fm){
    const int row0 = m0 + wm*64 + fm*16 + (hi<<2);
    #pragma unroll
    for (int p=0;p<4;++p){
      const int col = n0 + wn*64 + p*16 + l15;
      f32x4 v = acc[fm][p];
      #pragma unroll
      for (int r=0;r<4;++r) Cf[(size_t)(row0+r)*N + col] = v[r];
    }
  }
}

// ---------------- causal flash attention (v5 + defer-max) ------------------
__global__ __launch_bounds__(256, 2) void attn_kernel(
    const unsigned short* __restrict__ qh,
    const unsigned short* __restrict__ kh,
    const unsigned short* __restrict__ vT,
    unsigned short* __restrict__ ao)
{
  __shared__ __align__(16) unsigned short Ks[2][64*128];   // 32 KB
  __shared__ __align__(16) unsigned short Vs[2][128*64];   // 32 KB
  __shared__ __align__(16) unsigned short Ps[4][16*64];    //  8 KB -> 72 KB

  const int lane = threadIdx.x & 63;
  const int wid  = threadIdx.x >> 6;
  const int hi   = lane >> 4;
  const int l15  = lane & 15;
  const int pr = blockIdx.x;          // pair index 0..15
  const int bh = blockIdx.y;
  const int b_ = bh >> 4, h_ = bh & 15;

  const unsigned short* Qb = qh + (size_t)bh * SEQ * HDIM;
  const unsigned short* Kb = kh + (size_t)bh * SEQ * HDIM;
  const unsigned short* Vb = vT + (size_t)bh * HDIM * SEQ;

  const int qrowf[2] = { pr*64 + wid*16, (31-pr)*64 + wid*16 };

  auto stageKV = [&](int kg, int buf){
    #pragma unroll
    for (int i=0;i<4;++i){
      const int r  = (wid*4+i)*4 + (lane>>4);
      const int cb = ((lane&15)<<4) ^ ((r&7)<<4);
      gload_lds16(Kb + (size_t)(kg*64 + r)*HDIM + (cb>>1), &Ks[buf][0] + (wid*4+i)*512);
    }
    #pragma unroll
    for (int i=0;i<4;++i){
      const int d  = (wid*4+i)*8 + (lane>>3);
      const int cb = ((lane&7)<<4) ^ ((d&7)<<4);
      gload_lds16(Vb + (size_t)d*SEQ + kg*64 + (cb>>1), &Vs[buf][0] + (wid*4+i)*512);
    }
  };

  bf16x8 qf[2][4];
  #pragma unroll
  for (int fi=0; fi<2; ++fi){
    const int qr = qrowf[fi] + l15;
    #pragma unroll
    for (int ks = 0; ks < 4; ++ks)
      qf[fi][ks] = *reinterpret_cast<const bf16x8*>(Qb + (size_t)qr*HDIM + ks*32 + hi*8);
  }

  f32x4 oacc[2][8];
  #pragma unroll
  for (int fi=0;fi<2;++fi)
    #pragma unroll
    for (int t=0;t<8;++t) oacc[fi][t] = (f32x4){0.f,0.f,0.f,0.f};
  float mrun[2][4], lrun[2][4];
  #pragma unroll
  for (int fi=0;fi<2;++fi)
    #pragma unroll
    for (int r=0;r<4;++r){ mrun[fi][r] = -3.0e38f; lrun[fi][r] = 0.f; }

  const int nkt = 32 - pr;            // union of KV ranges for both frags

  stageKV(0, 0);
  __syncthreads();

  for (int kt = 0; kt < nkt; ++kt){
    const int cur = kt & 1;
    if (kt + 1 < nkt) stageKV(kt + 1, cur ^ 1);

    const bool lo_act = (kt <= pr);   // frag 0 active; frag 1 always active

    // ---- S = Q K^T (kf shared across active frags) ----
    f32x4 sacc[2][4];
    #pragma unroll
    for (int fi=0;fi<2;++fi)
      #pragma unroll
      for (int nt=0;nt<4;++nt) sacc[fi][nt] = (f32x4){0.f,0.f,0.f,0.f};
    __builtin_amdgcn_s_setprio(1);
    #pragma unroll
    for (int nt=0;nt<4;++nt){
      const int krow = nt*16 + l15;
      bf16x8 kf[4];
      #pragma unroll
      for (int ks=0;ks<4;++ks){
        const int cb = (ks*64 + (hi<<4)) ^ ((krow&7)<<4);
        kf[ks] = *reinterpret_cast<const bf16x8*>(&Ks[cur][0] + krow*128 + (cb>>1));
      }
      #pragma unroll
      for (int ks=0;ks<4;++ks)
        sacc[1][nt] = __builtin_amdgcn_mfma_f32_16x16x32_bf16(qf[1][ks], kf[ks], sacc[1][nt], 0,0,0);
      if (lo_act){
        #pragma unroll
        for (int ks=0;ks<4;++ks)
          sacc[0][nt] = __builtin_amdgcn_mfma_f32_16x16x32_bf16(qf[0][ks], kf[ks], sacc[0][nt], 0,0,0);
      }
    }
    __builtin_amdgcn_s_setprio(0);

    // ---- per-frag: mask, online softmax (defer-max), P write, PV ----
    char* pb = (char*)&Ps[wid][0];
    #pragma unroll
    for (int fi=0; fi<2; ++fi){
      if (fi == 0 && !lo_act) continue;

      if (kt*64 + 63 > qrowf[fi]){          // mask only on diagonal tiles
        #pragma unroll
        for (int nt=0;nt<4;++nt){
          const int key = kt*64 + nt*16 + l15;
          #pragma unroll
          for (int r=0;r<4;++r){
            const int qr = qrowf[fi] + hi*4 + r;
            if (key > qr) sacc[fi][nt][r] = -1.0e30f;
          }
        }
      }

      // defer-max (T13): skip rescale while max grows by <= 8 (log2 units;
      // P bounded by 2^8=256, bf16-safe).
      float mx[4]; float need = 0.f;
      #pragma unroll
      for (int r=0;r<4;++r){
        float m_ = fmaxf(fmaxf(sacc[fi][0][r], sacc[fi][1][r]),
                         fmaxf(sacc[fi][2][r], sacc[fi][3][r]));
        m_ = rmax16(m_);
        mx[r] = m_;
        need = fmaxf(need, m_ - mrun[fi][r]);
      }
      if (!__all(need <= 8.0f)){
        float fac[4];
        #pragma unroll
        for (int r=0;r<4;++r){
          const float mnew = fmaxf(mrun[fi][r], mx[r]);
          fac[r] = exp2f(mrun[fi][r] - mnew);
          mrun[fi][r] = mnew;
          lrun[fi][r] *= fac[r];
        }
        #pragma unroll
        for (int t=0;t<8;++t)
          #pragma unroll
          for (int r=0;r<4;++r) oacc[fi][t][r] *= fac[r];
      }
      #pragma unroll
      for (int r=0;r<4;++r){
        float ps = 0.f;
        #pragma unroll
        for (int nt=0;nt<4;++nt){
          const float p = exp2f(sacc[fi][nt][r] - mrun[fi][r]);
          sacc[fi][nt][r] = p;
          ps += p;
        }
        ps = rsum16(ps);
        lrun[fi][r] += ps;
      }

      // P (bf16) -> per-wave LDS (16 rows), swizzled
      #pragma unroll
      for (int nt=0;nt<4;++nt){
        const int keyb = (nt*16 + l15) << 1;
        #pragma unroll
        for (int r=0;r<4;++r){
          const int prow = hi*4 + r;
          *(unsigned short*)(pb + prow*128 + (keyb ^ ((prow&7)<<4))) = f2bf(sacc[fi][nt][r]);
        }
      }
      // wave-local LDS RAW: drain ds_writes before pa reads (rule #18)
      asm volatile("s_waitcnt lgkmcnt(0)" ::: "memory");
      __builtin_amdgcn_sched_barrier(0);

      bf16x8 pa[2];
      {
        const int prow = l15;
        #pragma unroll
        for (int ks=0;ks<2;++ks){
          const int pcb = (ks*64 + (hi<<4)) ^ ((prow&7)<<4);
          pa[ks] = *reinterpret_cast<const bf16x8*>(pb + prow*128 + pcb);
        }
      }
      __builtin_amdgcn_s_setprio(1);
      #pragma unroll
      for (int ks=0;ks<2;++ks){
        #pragma unroll
        for (int t=0;t<8;++t){
          const int drow = t*16 + l15;
          const int vcb = (ks*64 + (hi<<4)) ^ ((drow&7)<<4);
          bf16x8 vb = *reinterpret_cast<const bf16x8*>(&Vs[cur][0] + drow*64 + (vcb>>1));
          oacc[fi][t] = __builtin_amdgcn_mfma_f32_16x16x32_bf16(pa[ks], vb, oacc[fi][t], 0,0,0);
        }
      }
      __builtin_amdgcn_s_setprio(0);
    }

    __syncthreads();   // drains next-tile vmcnt + protects K/V buffers
  }

  // ---- epilogue: both frags ----
  #pragma unroll
  for (int fi=0;fi<2;++fi){
    float linv[4];
    #pragma unroll
    for (int r=0;r<4;++r) linv[r] = 1.0f / lrun[fi][r];
    #pragma unroll
    for (int t=0;t<8;++t){
      const int col = h_*HDIM + t*16 + l15;
      #pragma unroll
      for (int r=0;r<4;++r){
        const int s_ = qrowf[fi] + hi*4 + r;
        ao[(size_t)(b_*SEQ + s_)*DMODEL + col] = f2bf(oacc[fi][t][r] * linv[r]);
      }
    }
  }
}

// ---------------- launch ----------------
extern "C" void kernel_launch(void* const* d_in, const int* in_sizes, int n_in,
                              void* d_out, int out_size, void* d_ws, size_t ws_size,
                              hipStream_t stream)
{
  const float* x     = (const float*)d_in[0];
  const float* w_qkv = (const float*)d_in[1];
  const float* w_out = (const float*)d_in[2];
  float* out = (float*)d_out;

  unsigned short* xb    = (unsigned short*)d_ws;                 // 4096x2048
  unsigned short* wqkvb = xb    + (size_t)MTOT*DMODEL;           // 6144x2048
  unsigned short* woutb = wqkvb + (size_t)NQKV*DMODEL;           // 2048x2048
  unsigned short* qhb   = woutb + (size_t)DMODEL*DMODEL;         // (B,H,S,D)
  unsigned short* khb   = qhb   + (size_t)MTOT*DMODEL;           // (B,H,S,D)
  unsigned short* vtb   = khb   + (size_t)MTOT*DMODEL;           // (B,H,D,S)
  unsigned short* aob   = vtb   + (size_t)MTOT*DMODEL;           // 4096x2048
  float2* rtab          = (float2*)(aob + (size_t)MTOT*DMODEL);  // 2048x64 (1 MB)

  hipLaunchKernelGGL(cast3_kernel, dim3(1024), dim3(256), 0, stream,
                     x, xb, MTOT*DMODEL, w_qkv, wqkvb, NQKV*DMODEL, w_out, woutb, DMODEL*DMODEL,
                     rtab);
  hipLaunchKernelGGL((gemm2<0>), dim3(NQKV/256, MTOT/128), dim3(512), 0, stream,
                     xb, wqkvb, (float*)nullptr, qhb, khb, vtb, rtab, MTOT, NQKV, DMODEL);
  hipLaunchKernelGGL(attn_kernel, dim3(16, BATCH*NHEADS), dim3(256), 0, stream, qhb, khb, vtb, aob);
  hipLaunchKernelGGL(gemm_op, dim3(DMODEL/128, MTOT/128), dim3(256), 0, stream,
                     aob, woutb, out, MTOT, DMODEL, DMODEL);
}

// Round 16
// 246.066 us; speedup vs baseline: 1.0734x; 1.0172x over previous
//
#include <hip/hip_runtime.h>
#include <cstdint>
#include <cstddef>

#define NHEADS 16
#define HDIM   128
#define BATCH  2
#define SEQ    2048
#define DMODEL 2048
#define MTOT   (BATCH*SEQ)     // 4096
#define NQKV   (3*DMODEL)      // 6144

typedef __attribute__((ext_vector_type(8))) __bf16 bf16x8;
typedef __attribute__((ext_vector_type(4))) float f32x4;
typedef __attribute__((ext_vector_type(8))) unsigned short ushort8v;

__device__ __forceinline__ unsigned short f2bf(float f){
  __bf16 h = (__bf16)f;
  return __builtin_bit_cast(unsigned short, h);
}
__device__ __forceinline__ float bf2f(unsigned short s){
  return __uint_as_float(((uint32_t)s) << 16);
}
// async global->LDS, 16B per lane; LDS dest is wave-uniform base (+lane*16 by HW)
__device__ __forceinline__ void gload_lds16(const void* src, void* lds_base){
  __builtin_amdgcn_global_load_lds((const __attribute__((address_space(1))) unsigned int*)src,
                                   (__attribute__((address_space(3))) unsigned int*)lds_base,
                                   16, 0, 0);
}

// DPP 16-lane-row rotation butterflies (see round 2)
template<int CTRL>
__device__ __forceinline__ float dppmv(float x){
  return __uint_as_float((unsigned)__builtin_amdgcn_update_dpp(
      0, (int)__float_as_uint(x), CTRL, 0xF, 0xF, true));
}
__device__ __forceinline__ float rmax16(float x){
  x = fmaxf(x, dppmv<0x128>(x));
  x = fmaxf(x, dppmv<0x124>(x));
  x = fmaxf(x, dppmv<0x122>(x));
  x = fmaxf(x, dppmv<0x121>(x));
  return x;
}
__device__ __forceinline__ float rsum16(float x){
  x += dppmv<0x128>(x);
  x += dppmv<0x124>(x);
  x += dppmv<0x122>(x);
  x += dppmv<0x121>(x);
  return x;
}

// ------ fused cast fp32 -> bf16 (3 arrays) + rope cos/sin table build ------
__global__ void cast3_kernel(const float* __restrict__ s0, unsigned short* __restrict__ d0, int n0,
                             const float* __restrict__ s1, unsigned short* __restrict__ d1, int n1,
                             const float* __restrict__ s2, unsigned short* __restrict__ d2, int n2,
                             float2* __restrict__ tab){
  {
    const int i = blockIdx.x*blockDim.x + threadIdx.x;
    if (i < SEQ*64){
      const int j = i & 63, s = i >> 6;
      const float inv = exp2f(-(float)j * (13.287712379549449f/64.f));
      float sn, cs;
      sincosf((float)s * inv, &sn, &cs);
      tab[i] = make_float2(cs, sn);
    }
  }
  const int stride = gridDim.x*blockDim.x*8;
  const int base = (blockIdx.x*blockDim.x + threadIdx.x)*8;
  #pragma unroll 1
  for (int a = 0; a < 3; ++a){
    const float* s = a==0 ? s0 : (a==1 ? s1 : s2);
    unsigned short* d = a==0 ? d0 : (a==1 ? d1 : d2);
    const int n = a==0 ? n0 : (a==1 ? n1 : n2);
    for (int i = base; i < n; i += stride){
      float4 x = *reinterpret_cast<const float4*>(s + i);
      float4 y = *reinterpret_cast<const float4*>(s + i + 4);
      ushort8v o;
      o[0]=f2bf(x.x); o[1]=f2bf(x.y); o[2]=f2bf(x.z); o[3]=f2bf(x.w);
      o[4]=f2bf(y.x); o[5]=f2bf(y.y); o[6]=f2bf(y.z); o[7]=f2bf(y.w);
      *reinterpret_cast<ushort8v*>(d + i) = o;
    }
  }
}

// ---------- 128x256 B^T GEMM, BK=64, 2-phase counted-vmcnt (QKV) -----------
// r16: mid-phase barriers removed (hazard-audited). Per tile only 2 barriers:
//   P0-end  (guards P1's stage A(t+2)->cur vs all waves' P0 cur.A reads)
//   tile-end (after vmcnt; guards next-P0's stage B->nxt vs P1 B-hi reads)
// P0's B-stage->nxt is guarded by the PREVIOUS tile-end barrier.
template<int MODE>
__global__ __launch_bounds__(512, 2) void gemm2(
    const unsigned short* __restrict__ A,
    const unsigned short* __restrict__ Bw,
    float* __restrict__ Cf,
    unsigned short* __restrict__ qo,
    unsigned short* __restrict__ ko,
    unsigned short* __restrict__ vo,
    const float2* __restrict__ rtab,
    int M, int N, int K)
{
  __shared__ __align__(16) unsigned short smem[49152];
  auto lds = reinterpret_cast<unsigned short (*)[3][128*64]>(smem);  // [2][3][8192]

  const int lane = threadIdx.x & 63;
  const int wid  = threadIdx.x >> 6;
  const int wm = wid >> 2, wn = wid & 3;
  const int hi = lane >> 4;
  const int l15 = lane & 15;

  const int nwg = gridDim.x * gridDim.y;
  const int bid = blockIdx.y * gridDim.x + blockIdx.x;
  const int swz = (bid & 7) * (nwg >> 3) + (bid >> 3);
  const int by = swz & 31;
  const int bx = swz >> 5;
  const int m0 = by * 128;
  const int n0 = bx * 256;

  const int NT = K >> 6;

  auto stage = [&](const unsigned short* base, int row0, int k0, int buf, int slot){
    const int rlo = wid << 4;
    #pragma unroll
    for (int i=0;i<2;++i){
      const int r = rlo + i*8 + (lane>>3);
      const int csrc = ((lane&7) ^ (lane>>3)) << 3;   // elems
      gload_lds16(base + (size_t)(row0 + r)*K + k0 + csrc,
                  &lds[buf][slot][(rlo + i*8)*64]);
    }
  };
  auto frag = [&](const unsigned short* h, int r, int s){
    return *reinterpret_cast<const bf16x8*>(h + r*64 + ((s ^ (r&7)) << 3));
  };

  f32x4 acc[4][4];
  #pragma unroll
  for (int i=0;i<4;++i)
    #pragma unroll
    for (int j=0;j<4;++j) acc[i][j] = (f32x4){0.f,0.f,0.f,0.f};

  stage(A,  m0,      0, 0, 0);
  stage(Bw, n0,      0, 0, 1);
  stage(Bw, n0+128,  0, 0, 2);
  if (NT > 1){
    stage(A, m0, 64, 1, 0);
    asm volatile("s_waitcnt vmcnt(2)" ::: "memory");
  } else {
    asm volatile("s_waitcnt vmcnt(0)" ::: "memory");
  }
  __builtin_amdgcn_sched_barrier(0);
  __builtin_amdgcn_s_barrier();

  bf16x8 Ar[4][2];
  bf16x8 Br[2][2];

  auto tile_body = [&](int kt, int cur){
    const int nxt = cur ^ 1;
    const unsigned short* Ah = &lds[cur][0][0];
    const unsigned short* Bh = &lds[cur][1 + (wn>>1)][0];
    const int rbase = (wn & 1) * 64;

    // ===== P0: A + B-lo reads; stage t+1.B -> nxt; MFMA; P0-end barrier ====
    #pragma unroll
    for (int fm=0;fm<4;++fm)
      #pragma unroll
      for (int kk=0;kk<2;++kk)
        Ar[fm][kk] = frag(Ah, wm*64 + fm*16 + l15, kk*4 + hi);
    #pragma unroll
    for (int nf=0;nf<2;++nf)
      #pragma unroll
      for (int kk=0;kk<2;++kk)
        Br[nf][kk] = frag(Bh, rbase + nf*16 + l15, kk*4 + hi);
    if (kt+1 < NT){
      stage(Bw, n0,     (kt+1)*64, nxt, 1);
      stage(Bw, n0+128, (kt+1)*64, nxt, 2);
    }
    __builtin_amdgcn_sched_barrier(0);
    asm volatile("s_waitcnt lgkmcnt(0)" ::: "memory");
    __builtin_amdgcn_sched_barrier(0);
    __builtin_amdgcn_s_setprio(1);
    #pragma unroll
    for (int fm=0;fm<4;++fm){
      acc[fm][0] = __builtin_amdgcn_mfma_f32_16x16x32_bf16(Ar[fm][0], Br[0][0], acc[fm][0], 0,0,0);
      acc[fm][0] = __builtin_amdgcn_mfma_f32_16x16x32_bf16(Ar[fm][1], Br[0][1], acc[fm][0], 0,0,0);
      acc[fm][1] = __builtin_amdgcn_mfma_f32_16x16x32_bf16(Ar[fm][0], Br[1][0], acc[fm][1], 0,0,0);
      acc[fm][1] = __builtin_amdgcn_mfma_f32_16x16x32_bf16(Ar[fm][1], Br[1][1], acc[fm][1], 0,0,0);
    }
    __builtin_amdgcn_s_setprio(0);
    __builtin_amdgcn_sched_barrier(0);
    __builtin_amdgcn_s_barrier();           // P0-end (required)

    // ===== P1: B-hi reads; stage t+2.A -> cur; MFMA; vmcnt; tile-end =======
    #pragma unroll
    for (int nf=0;nf<2;++nf)
      #pragma unroll
      for (int kk=0;kk<2;++kk)
        Br[nf][kk] = frag(Bh, rbase + 32 + nf*16 + l15, kk*4 + hi);
    if (kt+2 < NT) stage(A, m0, (kt+2)*64, cur, 0);
    __builtin_amdgcn_sched_barrier(0);
    asm volatile("s_waitcnt lgkmcnt(0)" ::: "memory");
    __builtin_amdgcn_sched_barrier(0);
    __builtin_amdgcn_s_setprio(1);
    #pragma unroll
    for (int fm=0;fm<4;++fm){
      acc[fm][2] = __builtin_amdgcn_mfma_f32_16x16x32_bf16(Ar[fm][0], Br[0][0], acc[fm][2], 0,0,0);
      acc[fm][2] = __builtin_amdgcn_mfma_f32_16x16x32_bf16(Ar[fm][1], Br[0][1], acc[fm][2], 0,0,0);
      acc[fm][3] = __builtin_amdgcn_mfma_f32_16x16x32_bf16(Ar[fm][0], Br[1][0], acc[fm][3], 0,0,0);
      acc[fm][3] = __builtin_amdgcn_mfma_f32_16x16x32_bf16(Ar[fm][1], Br[1][1], acc[fm][3], 0,0,0);
    }
    __builtin_amdgcn_s_setprio(0);
    if (kt+2 < NT)      asm volatile("s_waitcnt vmcnt(2)" ::: "memory");
    else if (kt+1 < NT) asm volatile("s_waitcnt vmcnt(0)" ::: "memory");
    __builtin_amdgcn_sched_barrier(0);
    __builtin_amdgcn_s_barrier();           // tile-end (required)
  };

  for (int kt2 = 0; kt2 < NT; kt2 += 2){
    tile_body(kt2,     0);
    tile_body(kt2 + 1, 1);
  }

  // ---- epilogue ----
  if (MODE == 0 && (n0 >> 11) == 2){
    // V block: transpose 256(d) x 128(s) tile through LDS, coalesced vT store
    unsigned short* trsp = smem;                  // [256 d][136] ushorts
    #pragma unroll
    for (int fm=0;fm<4;++fm){
      const int srow = wm*64 + fm*16 + hi*4;
      #pragma unroll
      for (int p=0;p<4;++p){
        const int dcol = wn*64 + p*16 + l15;
        f32x4 v = acc[fm][p];
        ushort4 pk;
        pk.x=f2bf(v[0]); pk.y=f2bf(v[1]); pk.z=f2bf(v[2]); pk.w=f2bf(v[3]);
        *reinterpret_cast<ushort4*>(trsp + dcol*136 + srow) = pk;
      }
    }
    __syncthreads();
    const int bb  = m0 >> 11;
    const int ss0 = m0 & 2047;
    const size_t vrow = (size_t)(bb*2048 + (n0 - 4096));
    const int t = threadIdx.x;
    #pragma unroll
    for (int it=0; it<8; ++it){
      const int dl = it*32 + (t>>4);
      const int ch = t & 15;
      ushort8v val = *reinterpret_cast<const ushort8v*>(trsp + dl*136 + ch*8);
      *reinterpret_cast<ushort8v*>(vo + (vrow + dl)*SEQ + ss0 + ch*8) = val;
    }
  } else if (MODE == 0){
    // Q/K block: stage tile row-major in LDS, then fused rope (table) + store
    unsigned short* trsp = smem;                  // [128 rows][264] ushorts
    #pragma unroll
    for (int fm=0;fm<4;++fm){
      const int rowl = wm*64 + fm*16 + hi*4;
      #pragma unroll
      for (int p=0;p<4;++p){
        const int c = wn*64 + p*16 + l15;
        f32x4 v = acc[fm][p];
        #pragma unroll
        for (int r=0;r<4;++r) trsp[(rowl+r)*264 + c] = f2bf(v[r]);
      }
    }
    __syncthreads();
    const bool isq = (n0 >> 11) == 0;
    unsigned short* dst = isq ? qo : ko;
    const float QS = 0.08838834764831845f * 1.4426950408889634f;  // scale*log2e
    const int t = threadIdx.x;                    // 512 threads
    #pragma unroll
    for (int it=0; it<4; ++it){
      const int v = it*512 + t;
      const int rv = v >> 4;
      const int head = (v >> 3) & 1;
      const int jb = (v & 7) * 8;
      ushort8v a = *reinterpret_cast<const ushort8v*>(trsp + rv*264 + head*128 + jb);
      ushort8v b = *reinterpret_cast<const ushort8v*>(trsp + rv*264 + head*128 + 64 + jb);
      const int grow = m0 + rv;
      const int ss = grow & 2047, bb = grow >> 11;
      const int hh = ((n0 >> 7) & 15) + head;
      const float4* tb = reinterpret_cast<const float4*>(rtab + (size_t)ss*64 + jb);
      float csv[8], snv[8];
      #pragma unroll
      for (int q=0;q<4;++q){
        float4 tq = tb[q];
        csv[2*q]   = tq.x; snv[2*q]   = tq.y;
        csv[2*q+1] = tq.z; snv[2*q+1] = tq.w;
      }
      ushort8v o1, o2;
      #pragma unroll
      for (int e=0;e<8;++e){
        float x1 = bf2f(a[e]), x2 = bf2f(b[e]);
        float r1 = x1*csv[e] - x2*snv[e];
        float r2 = x2*csv[e] + x1*snv[e];
        if (isq){ r1 *= QS; r2 *= QS; }
        o1[e] = f2bf(r1); o2[e] = f2bf(r2);
      }
      unsigned short* base = dst + ((size_t)(bb*NHEADS+hh)*SEQ + ss)*HDIM;
      *reinterpret_cast<ushort8v*>(base + jb)      = o1;
      *reinterpret_cast<ushort8v*>(base + 64 + jb) = o2;
    }
  } else {
    #pragma unroll
    for (int fm=0;fm<4;++fm){
      const int row0 = m0 + wm*64 + fm*16 + (hi<<2);
      #pragma unroll
      for (int p=0;p<4;++p){
        const int col = n0 + wn*64 + p*16 + l15;
        f32x4 v = acc[fm][p];
        #pragma unroll
        for (int r=0;r<4;++r) Cf[(size_t)(row0+r)*N + col] = v[r];
      }
    }
  }
}

// ---------- 128x128 B^T GEMM, 4 waves, 64KB LDS -> 2 blocks/CU (out-proj) --
// r16: same 2-barrier-per-tile reduction as gemm2 (identical hazard audit).
__global__ __launch_bounds__(256, 2) void gemm_op(
    const unsigned short* __restrict__ A,
    const unsigned short* __restrict__ Bw,
    float* __restrict__ Cf,
    int M, int N, int K)
{
  __shared__ __align__(16) unsigned short smem[2][2][128*64];   // 64 KB
  const int lane = threadIdx.x & 63;
  const int wid  = threadIdx.x >> 6;          // 0..3
  const int wm = wid >> 1, wn = wid & 1;      // 2M x 2N, per-wave 64x64
  const int hi = lane >> 4;
  const int l15 = lane & 15;

  const int nwg = gridDim.x * gridDim.y;      // 512
  const int bid = blockIdx.y * gridDim.x + blockIdx.x;
  const int swz = (bid & 7) * (nwg >> 3) + (bid >> 3);
  const int by = swz & 31;
  const int bx = swz >> 5;                    // 0..15
  const int m0 = by * 128;
  const int n0 = bx * 128;

  const int NT = K >> 6;

  auto stage = [&](const unsigned short* base, int row0, int k0, int buf, int slot){
    const int rlo = wid << 5;                 // 32 rows per wave
    #pragma unroll
    for (int i=0;i<4;++i){
      const int r = rlo + i*8 + (lane>>3);
      const int csrc = ((lane&7) ^ (lane>>3)) << 3;
      gload_lds16(base + (size_t)(row0 + r)*K + k0 + csrc,
                  &smem[buf][slot][(rlo + i*8)*64]);
    }
  };
  auto frag = [&](const unsigned short* h, int r, int s){
    return *reinterpret_cast<const bf16x8*>(h + r*64 + ((s ^ (r&7)) << 3));
  };

  f32x4 acc[4][4];
  #pragma unroll
  for (int i=0;i<4;++i)
    #pragma unroll
    for (int j=0;j<4;++j) acc[i][j] = (f32x4){0.f,0.f,0.f,0.f};

  // prologue: t0 {A,B} + t1 {A}; vmcnt(4) => t0 landed, A(t1) in flight
  stage(A,  m0, 0, 0, 0);
  stage(Bw, n0, 0, 0, 1);
  if (NT > 1){
    stage(A, m0, 64, 1, 0);
    asm volatile("s_waitcnt vmcnt(4)" ::: "memory");
  } else {
    asm volatile("s_waitcnt vmcnt(0)" ::: "memory");
  }
  __builtin_amdgcn_sched_barrier(0);
  __builtin_amdgcn_s_barrier();

  bf16x8 Ar[4][2];
  bf16x8 Br[2][2];

  auto tile_body = [&](int kt, int cur){
    const int nxt = cur ^ 1;
    const unsigned short* Ah = &smem[cur][0][0];
    const unsigned short* Bh = &smem[cur][1][0];
    const int rbase = wn * 64;

    // ===== P0: A + B-lo reads; stage t+1.B -> nxt; MFMA; P0-end barrier ====
    #pragma unroll
    for (int fm=0;fm<4;++fm)
      #pragma unroll
      for (int kk=0;kk<2;++kk)
        Ar[fm][kk] = frag(Ah, wm*64 + fm*16 + l15, kk*4 + hi);
    #pragma unroll
    for (int nf=0;nf<2;++nf)
      #pragma unroll
      for (int kk=0;kk<2;++kk)
        Br[nf][kk] = frag(Bh, rbase + nf*16 + l15, kk*4 + hi);
    if (kt+1 < NT) stage(Bw, n0, (kt+1)*64, nxt, 1);
    __builtin_amdgcn_sched_barrier(0);
    asm volatile("s_waitcnt lgkmcnt(0)" ::: "memory");
    __builtin_amdgcn_sched_barrier(0);
    __builtin_amdgcn_s_setprio(1);
    #pragma unroll
    for (int fm=0;fm<4;++fm){
      acc[fm][0] = __builtin_amdgcn_mfma_f32_16x16x32_bf16(Ar[fm][0], Br[0][0], acc[fm][0], 0,0,0);
      acc[fm][0] = __builtin_amdgcn_mfma_f32_16x16x32_bf16(Ar[fm][1], Br[0][1], acc[fm][0], 0,0,0);
      acc[fm][1] = __builtin_amdgcn_mfma_f32_16x16x32_bf16(Ar[fm][0], Br[1][0], acc[fm][1], 0,0,0);
      acc[fm][1] = __builtin_amdgcn_mfma_f32_16x16x32_bf16(Ar[fm][1], Br[1][1], acc[fm][1], 0,0,0);
    }
    __builtin_amdgcn_s_setprio(0);
    __builtin_amdgcn_sched_barrier(0);
    __builtin_amdgcn_s_barrier();           // P0-end (required)

    // ===== P1: B-hi reads; stage t+2.A -> cur; MFMA; vmcnt; tile-end =======
    #pragma unroll
    for (int nf=0;nf<2;++nf)
      #pragma unroll
      for (int kk=0;kk<2;++kk)
        Br[nf][kk] = frag(Bh, rbase + 32 + nf*16 + l15, kk*4 + hi);
    if (kt+2 < NT) stage(A, m0, (kt+2)*64, cur, 0);
    __builtin_amdgcn_sched_barrier(0);
    asm volatile("s_waitcnt lgkmcnt(0)" ::: "memory");
    __builtin_amdgcn_sched_barrier(0);
    __builtin_amdgcn_s_setprio(1);
    #pragma unroll
    for (int fm=0;fm<4;++fm){
      acc[fm][2] = __builtin_amdgcn_mfma_f32_16x16x32_bf16(Ar[fm][0], Br[0][0], acc[fm][2], 0,0,0);
      acc[fm][2] = __builtin_amdgcn_mfma_f32_16x16x32_bf16(Ar[fm][1], Br[0][1], acc[fm][2], 0,0,0);
      acc[fm][3] = __builtin_amdgcn_mfma_f32_16x16x32_bf16(Ar[fm][0], Br[1][0], acc[fm][3], 0,0,0);
      acc[fm][3] = __builtin_amdgcn_mfma_f32_16x16x32_bf16(Ar[fm][1], Br[1][1], acc[fm][3], 0,0,0);
    }
    __builtin_amdgcn_s_setprio(0);
    if (kt+2 < NT)      asm volatile("s_waitcnt vmcnt(4)" ::: "memory");
    else if (kt+1 < NT) asm volatile("s_waitcnt vmcnt(0)" ::: "memory");
    __builtin_amdgcn_sched_barrier(0);
    __builtin_amdgcn_s_barrier();           // tile-end (required)
  };

  for (int kt2 = 0; kt2 < NT; kt2 += 2){
    tile_body(kt2,     0);
    tile_body(kt2 + 1, 1);
  }

  #pragma unroll
  for (int fm=0;fm<4;++fm){
    const int row0 = m0 + wm*64 + fm*16 + (hi<<2);
    #pragma unroll
    for (int p=0;p<4;++p){
      const int col = n0 + wn*64 + p*16 + l15;
      f32x4 v = acc[fm][p];
      #pragma unroll
      for (int r=0;r<4;++r) Cf[(size_t)(row0+r)*N + col] = v[r];
    }
  }
}

// ---------------- causal flash attention (v5 + defer-max, unchanged) -------
__global__ __launch_bounds__(256, 2) void attn_kernel(
    const unsigned short* __restrict__ qh,
    const unsigned short* __restrict__ kh,
    const unsigned short* __restrict__ vT,
    unsigned short* __restrict__ ao)
{
  __shared__ __align__(16) unsigned short Ks[2][64*128];   // 32 KB
  __shared__ __align__(16) unsigned short Vs[2][128*64];   // 32 KB
  __shared__ __align__(16) unsigned short Ps[4][16*64];    //  8 KB -> 72 KB

  const int lane = threadIdx.x & 63;
  const int wid  = threadIdx.x >> 6;
  const int hi   = lane >> 4;
  const int l15  = lane & 15;
  const int pr = blockIdx.x;          // pair index 0..15
  const int bh = blockIdx.y;
  const int b_ = bh >> 4, h_ = bh & 15;

  const unsigned short* Qb = qh + (size_t)bh * SEQ * HDIM;
  const unsigned short* Kb = kh + (size_t)bh * SEQ * HDIM;
  const unsigned short* Vb = vT + (size_t)bh * HDIM * SEQ;

  const int qrowf[2] = { pr*64 + wid*16, (31-pr)*64 + wid*16 };

  auto stageKV = [&](int kg, int buf){
    #pragma unroll
    for (int i=0;i<4;++i){
      const int r  = (wid*4+i)*4 + (lane>>4);
      const int cb = ((lane&15)<<4) ^ ((r&7)<<4);
      gload_lds16(Kb + (size_t)(kg*64 + r)*HDIM + (cb>>1), &Ks[buf][0] + (wid*4+i)*512);
    }
    #pragma unroll
    for (int i=0;i<4;++i){
      const int d  = (wid*4+i)*8 + (lane>>3);
      const int cb = ((lane&7)<<4) ^ ((d&7)<<4);
      gload_lds16(Vb + (size_t)d*SEQ + kg*64 + (cb>>1), &Vs[buf][0] + (wid*4+i)*512);
    }
  };

  bf16x8 qf[2][4];
  #pragma unroll
  for (int fi=0; fi<2; ++fi){
    const int qr = qrowf[fi] + l15;
    #pragma unroll
    for (int ks = 0; ks < 4; ++ks)
      qf[fi][ks] = *reinterpret_cast<const bf16x8*>(Qb + (size_t)qr*HDIM + ks*32 + hi*8);
  }

  f32x4 oacc[2][8];
  #pragma unroll
  for (int fi=0;fi<2;++fi)
    #pragma unroll
    for (int t=0;t<8;++t) oacc[fi][t] = (f32x4){0.f,0.f,0.f,0.f};
  float mrun[2][4], lrun[2][4];
  #pragma unroll
  for (int fi=0;fi<2;++fi)
    #pragma unroll
    for (int r=0;r<4;++r){ mrun[fi][r] = -3.0e38f; lrun[fi][r] = 0.f; }

  const int nkt = 32 - pr;            // union of KV ranges for both frags

  stageKV(0, 0);
  __syncthreads();

  for (int kt = 0; kt < nkt; ++kt){
    const int cur = kt & 1;
    if (kt + 1 < nkt) stageKV(kt + 1, cur ^ 1);

    const bool lo_act = (kt <= pr);   // frag 0 active; frag 1 always active

    // ---- S = Q K^T (kf shared across active frags) ----
    f32x4 sacc[2][4];
    #pragma unroll
    for (int fi=0;fi<2;++fi)
      #pragma unroll
      for (int nt=0;nt<4;++nt) sacc[fi][nt] = (f32x4){0.f,0.f,0.f,0.f};
    __builtin_amdgcn_s_setprio(1);
    #pragma unroll
    for (int nt=0;nt<4;++nt){
      const int krow = nt*16 + l15;
      bf16x8 kf[4];
      #pragma unroll
      for (int ks=0;ks<4;++ks){
        const int cb = (ks*64 + (hi<<4)) ^ ((krow&7)<<4);
        kf[ks] = *reinterpret_cast<const bf16x8*>(&Ks[cur][0] + krow*128 + (cb>>1));
      }
      #pragma unroll
      for (int ks=0;ks<4;++ks)
        sacc[1][nt] = __builtin_amdgcn_mfma_f32_16x16x32_bf16(qf[1][ks], kf[ks], sacc[1][nt], 0,0,0);
      if (lo_act){
        #pragma unroll
        for (int ks=0;ks<4;++ks)
          sacc[0][nt] = __builtin_amdgcn_mfma_f32_16x16x32_bf16(qf[0][ks], kf[ks], sacc[0][nt], 0,0,0);
      }
    }
    __builtin_amdgcn_s_setprio(0);

    // ---- per-frag: mask, online softmax (defer-max), P write, PV ----
    char* pb = (char*)&Ps[wid][0];
    #pragma unroll
    for (int fi=0; fi<2; ++fi){
      if (fi == 0 && !lo_act) continue;

      if (kt*64 + 63 > qrowf[fi]){          // mask only on diagonal tiles
        #pragma unroll
        for (int nt=0;nt<4;++nt){
          const int key = kt*64 + nt*16 + l15;
          #pragma unroll
          for (int r=0;r<4;++r){
            const int qr = qrowf[fi] + hi*4 + r;
            if (key > qr) sacc[fi][nt][r] = -1.0e30f;
          }
        }
      }

      // defer-max (T13): skip rescale while max grows by <= 8 (log2 units;
      // P bounded by 2^8=256, bf16-safe).
      float mx[4]; float need = 0.f;
      #pragma unroll
      for (int r=0;r<4;++r){
        float m_ = fmaxf(fmaxf(sacc[fi][0][r], sacc[fi][1][r]),
                         fmaxf(sacc[fi][2][r], sacc[fi][3][r]));
        m_ = rmax16(m_);
        mx[r] = m_;
        need = fmaxf(need, m_ - mrun[fi][r]);
      }
      if (!__all(need <= 8.0f)){
        float fac[4];
        #pragma unroll
        for (int r=0;r<4;++r){
          const float mnew = fmaxf(mrun[fi][r], mx[r]);
          fac[r] = exp2f(mrun[fi][r] - mnew);
          mrun[fi][r] = mnew;
          lrun[fi][r] *= fac[r];
        }
        #pragma unroll
        for (int t=0;t<8;++t)
          #pragma unroll
          for (int r=0;r<4;++r) oacc[fi][t][r] *= fac[r];
      }
      #pragma unroll
      for (int r=0;r<4;++r){
        float ps = 0.f;
        #pragma unroll
        for (int nt=0;nt<4;++nt){
          const float p = exp2f(sacc[fi][nt][r] - mrun[fi][r]);
          sacc[fi][nt][r] = p;
          ps += p;
        }
        ps = rsum16(ps);
        lrun[fi][r] += ps;
      }

      // P (bf16) -> per-wave LDS (16 rows), swizzled
      #pragma unroll
      for (int nt=0;nt<4;++nt){
        const int keyb = (nt*16 + l15) << 1;
        #pragma unroll
        for (int r=0;r<4;++r){
          const int prow = hi*4 + r;
          *(unsigned short*)(pb + prow*128 + (keyb ^ ((prow&7)<<4))) = f2bf(sacc[fi][nt][r]);
        }
      }
      // wave-local LDS RAW: drain ds_writes before pa reads (rule #18)
      asm volatile("s_waitcnt lgkmcnt(0)" ::: "memory");
      __builtin_amdgcn_sched_barrier(0);

      bf16x8 pa[2];
      {
        const int prow = l15;
        #pragma unroll
        for (int ks=0;ks<2;++ks){
          const int pcb = (ks*64 + (hi<<4)) ^ ((prow&7)<<4);
          pa[ks] = *reinterpret_cast<const bf16x8*>(pb + prow*128 + pcb);
        }
      }
      __builtin_amdgcn_s_setprio(1);
      #pragma unroll
      for (int ks=0;ks<2;++ks){
        #pragma unroll
        for (int t=0;t<8;++t){
          const int drow = t*16 + l15;
          const int vcb = (ks*64 + (hi<<4)) ^ ((drow&7)<<4);
          bf16x8 vb = *reinterpret_cast<const bf16x8*>(&Vs[cur][0] + drow*64 + (vcb>>1));
          oacc[fi][t] = __builtin_amdgcn_mfma_f32_16x16x32_bf16(pa[ks], vb, oacc[fi][t], 0,0,0);
        }
      }
      __builtin_amdgcn_s_setprio(0);
    }

    __syncthreads();   // drains next-tile vmcnt + protects K/V buffers
  }

  // ---- epilogue: both frags ----
  #pragma unroll
  for (int fi=0;fi<2;++fi){
    float linv[4];
    #pragma unroll
    for (int r=0;r<4;++r) linv[r] = 1.0f / lrun[fi][r];
    #pragma unroll
    for (int t=0;t<8;++t){
      const int col = h_*HDIM + t*16 + l15;
      #pragma unroll
      for (int r=0;r<4;++r){
        const int s_ = qrowf[fi] + hi*4 + r;
        ao[(size_t)(b_*SEQ + s_)*DMODEL + col] = f2bf(oacc[fi][t][r] * linv[r]);
      }
    }
  }
}

// ---------------- launch ----------------
extern "C" void kernel_launch(void* const* d_in, const int* in_sizes, int n_in,
                              void* d_out, int out_size, void* d_ws, size_t ws_size,
                              hipStream_t stream)
{
  const float* x     = (const float*)d_in[0];
  const float* w_qkv = (const float*)d_in[1];
  const float* w_out = (const float*)d_in[2];
  float* out = (float*)d_out;

  unsigned short* xb    = (unsigned short*)d_ws;                 // 4096x2048
  unsigned short* wqkvb = xb    + (size_t)MTOT*DMODEL;           // 6144x2048
  unsigned short* woutb = wqkvb + (size_t)NQKV*DMODEL;           // 2048x2048
  unsigned short* qhb   = woutb + (size_t)DMODEL*DMODEL;         // (B,H,S,D)
  unsigned short* khb   = qhb   + (size_t)MTOT*DMODEL;           // (B,H,S,D)
  unsigned short* vtb   = khb   + (size_t)MTOT*DMODEL;           // (B,H,D,S)
  unsigned short* aob   = vtb   + (size_t)MTOT*DMODEL;           // 4096x2048
  float2* rtab          = (float2*)(aob + (size_t)MTOT*DMODEL);  // 2048x64 (1 MB)

  hipLaunchKernelGGL(cast3_kernel, dim3(1024), dim3(256), 0, stream,
                     x, xb, MTOT*DMODEL, w_qkv, wqkvb, NQKV*DMODEL, w_out, woutb, DMODEL*DMODEL,
                     rtab);
  hipLaunchKernelGGL((gemm2<0>), dim3(NQKV/256, MTOT/128), dim3(512), 0, stream,
                     xb, wqkvb, (float*)nullptr, qhb, khb, vtb, rtab, MTOT, NQKV, DMODEL);
  hipLaunchKernelGGL(attn_kernel, dim3(16, BATCH*NHEADS), dim3(256), 0, stream, qhb, khb, vtb, aob);
  hipLaunchKernelGGL(gemm_op, dim3(DMODEL/128, MTOT/128), dim3(256), 0, stream,
                     aob, woutb, out, MTOT, DMODEL, DMODEL);
}

// Round 17
// 245.325 us; speedup vs baseline: 1.0767x; 1.0030x over previous
//
#include <hip/hip_runtime.h>
#include <cstdint>
#include <cstddef>

#define NHEADS 16
#define HDIM   128
#define BATCH  2
#define SEQ    2048
#define DMODEL 2048
#define MTOT   (BATCH*SEQ)     // 4096
#define NQKV   (3*DMODEL)      // 6144

typedef __attribute__((ext_vector_type(8))) __bf16 bf16x8;
typedef __attribute__((ext_vector_type(4))) float f32x4;
typedef __attribute__((ext_vector_type(8))) unsigned short ushort8v;

__device__ __forceinline__ unsigned short f2bf(float f){
  __bf16 h = (__bf16)f;
  return __builtin_bit_cast(unsigned short, h);
}
__device__ __forceinline__ float bf2f(unsigned short s){
  return __uint_as_float(((uint32_t)s) << 16);
}
// async global->LDS, 16B per lane; LDS dest is wave-uniform base (+lane*16 by HW)
__device__ __forceinline__ void gload_lds16(const void* src, void* lds_base){
  __builtin_amdgcn_global_load_lds((const __attribute__((address_space(1))) unsigned int*)src,
                                   (__attribute__((address_space(3))) unsigned int*)lds_base,
                                   16, 0, 0);
}

// DPP 16-lane-row rotation butterflies (see round 2)
template<int CTRL>
__device__ __forceinline__ float dppmv(float x){
  return __uint_as_float((unsigned)__builtin_amdgcn_update_dpp(
      0, (int)__float_as_uint(x), CTRL, 0xF, 0xF, true));
}
__device__ __forceinline__ float rmax16(float x){
  x = fmaxf(x, dppmv<0x128>(x));
  x = fmaxf(x, dppmv<0x124>(x));
  x = fmaxf(x, dppmv<0x122>(x));
  x = fmaxf(x, dppmv<0x121>(x));
  return x;
}
__device__ __forceinline__ float rsum16(float x){
  x += dppmv<0x128>(x);
  x += dppmv<0x124>(x);
  x += dppmv<0x122>(x);
  x += dppmv<0x121>(x);
  return x;
}

// ------ fused cast fp32 -> bf16 (3 arrays) + rope cos/sin table build ------
__global__ void cast3_kernel(const float* __restrict__ s0, unsigned short* __restrict__ d0, int n0,
                             const float* __restrict__ s1, unsigned short* __restrict__ d1, int n1,
                             const float* __restrict__ s2, unsigned short* __restrict__ d2, int n2,
                             float2* __restrict__ tab){
  {
    const int i = blockIdx.x*blockDim.x + threadIdx.x;
    if (i < SEQ*64){
      const int j = i & 63, s = i >> 6;
      const float inv = exp2f(-(float)j * (13.287712379549449f/64.f));
      float sn, cs;
      sincosf((float)s * inv, &sn, &cs);
      tab[i] = make_float2(cs, sn);
    }
  }
  const int stride = gridDim.x*blockDim.x*8;
  const int base = (blockIdx.x*blockDim.x + threadIdx.x)*8;
  #pragma unroll 1
  for (int a = 0; a < 3; ++a){
    const float* s = a==0 ? s0 : (a==1 ? s1 : s2);
    unsigned short* d = a==0 ? d0 : (a==1 ? d1 : d2);
    const int n = a==0 ? n0 : (a==1 ? n1 : n2);
    for (int i = base; i < n; i += stride){
      float4 x = *reinterpret_cast<const float4*>(s + i);
      float4 y = *reinterpret_cast<const float4*>(s + i + 4);
      ushort8v o;
      o[0]=f2bf(x.x); o[1]=f2bf(x.y); o[2]=f2bf(x.z); o[3]=f2bf(x.w);
      o[4]=f2bf(y.x); o[5]=f2bf(y.y); o[6]=f2bf(y.z); o[7]=f2bf(y.w);
      *reinterpret_cast<ushort8v*>(d + i) = o;
    }
  }
}

// ---------- 128x256 B^T GEMM, BK=64, 2-phase counted-vmcnt (QKV) -----------
// r16 barrier-minimal: per tile only {P0-end, tile-end} barriers (hazard-
// audited). MODE 0 epilogues: V -> LDS transpose + vT store; Q/K -> fused
// rope via (cos,sin) table + head store.
template<int MODE>
__global__ __launch_bounds__(512, 2) void gemm2(
    const unsigned short* __restrict__ A,
    const unsigned short* __restrict__ Bw,
    float* __restrict__ Cf,
    unsigned short* __restrict__ qo,
    unsigned short* __restrict__ ko,
    unsigned short* __restrict__ vo,
    const float2* __restrict__ rtab,
    int M, int N, int K)
{
  __shared__ __align__(16) unsigned short smem[49152];
  auto lds = reinterpret_cast<unsigned short (*)[3][128*64]>(smem);  // [2][3][8192]

  const int lane = threadIdx.x & 63;
  const int wid  = threadIdx.x >> 6;
  const int wm = wid >> 2, wn = wid & 3;
  const int hi = lane >> 4;
  const int l15 = lane & 15;

  const int nwg = gridDim.x * gridDim.y;
  const int bid = blockIdx.y * gridDim.x + blockIdx.x;
  const int swz = (bid & 7) * (nwg >> 3) + (bid >> 3);
  const int by = swz & 31;
  const int bx = swz >> 5;
  const int m0 = by * 128;
  const int n0 = bx * 256;

  const int NT = K >> 6;

  auto stage = [&](const unsigned short* base, int row0, int k0, int buf, int slot){
    const int rlo = wid << 4;
    #pragma unroll
    for (int i=0;i<2;++i){
      const int r = rlo + i*8 + (lane>>3);
      const int csrc = ((lane&7) ^ (lane>>3)) << 3;   // elems
      gload_lds16(base + (size_t)(row0 + r)*K + k0 + csrc,
                  &lds[buf][slot][(rlo + i*8)*64]);
    }
  };
  auto frag = [&](const unsigned short* h, int r, int s){
    return *reinterpret_cast<const bf16x8*>(h + r*64 + ((s ^ (r&7)) << 3));
  };

  f32x4 acc[4][4];
  #pragma unroll
  for (int i=0;i<4;++i)
    #pragma unroll
    for (int j=0;j<4;++j) acc[i][j] = (f32x4){0.f,0.f,0.f,0.f};

  stage(A,  m0,      0, 0, 0);
  stage(Bw, n0,      0, 0, 1);
  stage(Bw, n0+128,  0, 0, 2);
  if (NT > 1){
    stage(A, m0, 64, 1, 0);
    asm volatile("s_waitcnt vmcnt(2)" ::: "memory");
  } else {
    asm volatile("s_waitcnt vmcnt(0)" ::: "memory");
  }
  __builtin_amdgcn_sched_barrier(0);
  __builtin_amdgcn_s_barrier();

  bf16x8 Ar[4][2];
  bf16x8 Br[2][2];

  auto tile_body = [&](int kt, int cur){
    const int nxt = cur ^ 1;
    const unsigned short* Ah = &lds[cur][0][0];
    const unsigned short* Bh = &lds[cur][1 + (wn>>1)][0];
    const int rbase = (wn & 1) * 64;

    // ===== P0: A + B-lo reads; stage t+1.B -> nxt; MFMA; P0-end barrier ====
    #pragma unroll
    for (int fm=0;fm<4;++fm)
      #pragma unroll
      for (int kk=0;kk<2;++kk)
        Ar[fm][kk] = frag(Ah, wm*64 + fm*16 + l15, kk*4 + hi);
    #pragma unroll
    for (int nf=0;nf<2;++nf)
      #pragma unroll
      for (int kk=0;kk<2;++kk)
        Br[nf][kk] = frag(Bh, rbase + nf*16 + l15, kk*4 + hi);
    if (kt+1 < NT){
      stage(Bw, n0,     (kt+1)*64, nxt, 1);
      stage(Bw, n0+128, (kt+1)*64, nxt, 2);
    }
    __builtin_amdgcn_sched_barrier(0);
    asm volatile("s_waitcnt lgkmcnt(0)" ::: "memory");
    __builtin_amdgcn_sched_barrier(0);
    __builtin_amdgcn_s_setprio(1);
    #pragma unroll
    for (int fm=0;fm<4;++fm){
      acc[fm][0] = __builtin_amdgcn_mfma_f32_16x16x32_bf16(Ar[fm][0], Br[0][0], acc[fm][0], 0,0,0);
      acc[fm][0] = __builtin_amdgcn_mfma_f32_16x16x32_bf16(Ar[fm][1], Br[0][1], acc[fm][0], 0,0,0);
      acc[fm][1] = __builtin_amdgcn_mfma_f32_16x16x32_bf16(Ar[fm][0], Br[1][0], acc[fm][1], 0,0,0);
      acc[fm][1] = __builtin_amdgcn_mfma_f32_16x16x32_bf16(Ar[fm][1], Br[1][1], acc[fm][1], 0,0,0);
    }
    __builtin_amdgcn_s_setprio(0);
    __builtin_amdgcn_sched_barrier(0);
    __builtin_amdgcn_s_barrier();           // P0-end (required)

    // ===== P1: B-hi reads; stage t+2.A -> cur; MFMA; vmcnt; tile-end =======
    #pragma unroll
    for (int nf=0;nf<2;++nf)
      #pragma unroll
      for (int kk=0;kk<2;++kk)
        Br[nf][kk] = frag(Bh, rbase + 32 + nf*16 + l15, kk*4 + hi);
    if (kt+2 < NT) stage(A, m0, (kt+2)*64, cur, 0);
    __builtin_amdgcn_sched_barrier(0);
    asm volatile("s_waitcnt lgkmcnt(0)" ::: "memory");
    __builtin_amdgcn_sched_barrier(0);
    __builtin_amdgcn_s_setprio(1);
    #pragma unroll
    for (int fm=0;fm<4;++fm){
      acc[fm][2] = __builtin_amdgcn_mfma_f32_16x16x32_bf16(Ar[fm][0], Br[0][0], acc[fm][2], 0,0,0);
      acc[fm][2] = __builtin_amdgcn_mfma_f32_16x16x32_bf16(Ar[fm][1], Br[0][1], acc[fm][2], 0,0,0);
      acc[fm][3] = __builtin_amdgcn_mfma_f32_16x16x32_bf16(Ar[fm][0], Br[1][0], acc[fm][3], 0,0,0);
      acc[fm][3] = __builtin_amdgcn_mfma_f32_16x16x32_bf16(Ar[fm][1], Br[1][1], acc[fm][3], 0,0,0);
    }
    __builtin_amdgcn_s_setprio(0);
    if (kt+2 < NT)      asm volatile("s_waitcnt vmcnt(2)" ::: "memory");
    else if (kt+1 < NT) asm volatile("s_waitcnt vmcnt(0)" ::: "memory");
    __builtin_amdgcn_sched_barrier(0);
    __builtin_amdgcn_s_barrier();           // tile-end (required)
  };

  for (int kt2 = 0; kt2 < NT; kt2 += 2){
    tile_body(kt2,     0);
    tile_body(kt2 + 1, 1);
  }

  // ---- epilogue ----
  if (MODE == 0 && (n0 >> 11) == 2){
    // V block: transpose 256(d) x 128(s) tile through LDS, coalesced vT store
    unsigned short* trsp = smem;                  // [256 d][136] ushorts
    #pragma unroll
    for (int fm=0;fm<4;++fm){
      const int srow = wm*64 + fm*16 + hi*4;
      #pragma unroll
      for (int p=0;p<4;++p){
        const int dcol = wn*64 + p*16 + l15;
        f32x4 v = acc[fm][p];
        ushort4 pk;
        pk.x=f2bf(v[0]); pk.y=f2bf(v[1]); pk.z=f2bf(v[2]); pk.w=f2bf(v[3]);
        *reinterpret_cast<ushort4*>(trsp + dcol*136 + srow) = pk;
      }
    }
    __syncthreads();
    const int bb  = m0 >> 11;
    const int ss0 = m0 & 2047;
    const size_t vrow = (size_t)(bb*2048 + (n0 - 4096));
    const int t = threadIdx.x;
    #pragma unroll
    for (int it=0; it<8; ++it){
      const int dl = it*32 + (t>>4);
      const int ch = t & 15;
      ushort8v val = *reinterpret_cast<const ushort8v*>(trsp + dl*136 + ch*8);
      *reinterpret_cast<ushort8v*>(vo + (vrow + dl)*SEQ + ss0 + ch*8) = val;
    }
  } else if (MODE == 0){
    // Q/K block: stage tile row-major in LDS, then fused rope (table) + store
    unsigned short* trsp = smem;                  // [128 rows][264] ushorts
    #pragma unroll
    for (int fm=0;fm<4;++fm){
      const int rowl = wm*64 + fm*16 + hi*4;
      #pragma unroll
      for (int p=0;p<4;++p){
        const int c = wn*64 + p*16 + l15;
        f32x4 v = acc[fm][p];
        #pragma unroll
        for (int r=0;r<4;++r) trsp[(rowl+r)*264 + c] = f2bf(v[r]);
      }
    }
    __syncthreads();
    const bool isq = (n0 >> 11) == 0;
    unsigned short* dst = isq ? qo : ko;
    const float QS = 0.08838834764831845f * 1.4426950408889634f;  // scale*log2e
    const int t = threadIdx.x;                    // 512 threads
    #pragma unroll
    for (int it=0; it<4; ++it){
      const int v = it*512 + t;
      const int rv = v >> 4;
      const int head = (v >> 3) & 1;
      const int jb = (v & 7) * 8;
      ushort8v a = *reinterpret_cast<const ushort8v*>(trsp + rv*264 + head*128 + jb);
      ushort8v b = *reinterpret_cast<const ushort8v*>(trsp + rv*264 + head*128 + 64 + jb);
      const int grow = m0 + rv;
      const int ss = grow & 2047, bb = grow >> 11;
      const int hh = ((n0 >> 7) & 15) + head;
      const float4* tb = reinterpret_cast<const float4*>(rtab + (size_t)ss*64 + jb);
      float csv[8], snv[8];
      #pragma unroll
      for (int q=0;q<4;++q){
        float4 tq = tb[q];
        csv[2*q]   = tq.x; snv[2*q]   = tq.y;
        csv[2*q+1] = tq.z; snv[2*q+1] = tq.w;
      }
      ushort8v o1, o2;
      #pragma unroll
      for (int e=0;e<8;++e){
        float x1 = bf2f(a[e]), x2 = bf2f(b[e]);
        float r1 = x1*csv[e] - x2*snv[e];
        float r2 = x2*csv[e] + x1*snv[e];
        if (isq){ r1 *= QS; r2 *= QS; }
        o1[e] = f2bf(r1); o2[e] = f2bf(r2);
      }
      unsigned short* base = dst + ((size_t)(bb*NHEADS+hh)*SEQ + ss)*HDIM;
      *reinterpret_cast<ushort8v*>(base + jb)      = o1;
      *reinterpret_cast<ushort8v*>(base + 64 + jb) = o2;
    }
  } else {
    #pragma unroll
    for (int fm=0;fm<4;++fm){
      const int row0 = m0 + wm*64 + fm*16 + (hi<<2);
      #pragma unroll
      for (int p=0;p<4;++p){
        const int col = n0 + wn*64 + p*16 + l15;
        f32x4 v = acc[fm][p];
        #pragma unroll
        for (int r=0;r<4;++r) Cf[(size_t)(row0+r)*N + col] = v[r];
      }
    }
  }
}

// ---------- 128x128 B^T GEMM, 4 waves, 64KB LDS -> 2 blocks/CU (out-proj) --
__global__ __launch_bounds__(256, 2) void gemm_op(
    const unsigned short* __restrict__ A,
    const unsigned short* __restrict__ Bw,
    float* __restrict__ Cf,
    int M, int N, int K)
{
  __shared__ __align__(16) unsigned short smem[2][2][128*64];   // 64 KB
  const int lane = threadIdx.x & 63;
  const int wid  = threadIdx.x >> 6;          // 0..3
  const int wm = wid >> 1, wn = wid & 1;      // 2M x 2N, per-wave 64x64
  const int hi = lane >> 4;
  const int l15 = lane & 15;

  const int nwg = gridDim.x * gridDim.y;      // 512
  const int bid = blockIdx.y * gridDim.x + blockIdx.x;
  const int swz = (bid & 7) * (nwg >> 3) + (bid >> 3);
  const int by = swz & 31;
  const int bx = swz >> 5;                    // 0..15
  const int m0 = by * 128;
  const int n0 = bx * 128;

  const int NT = K >> 6;

  auto stage = [&](const unsigned short* base, int row0, int k0, int buf, int slot){
    const int rlo = wid << 5;                 // 32 rows per wave
    #pragma unroll
    for (int i=0;i<4;++i){
      const int r = rlo + i*8 + (lane>>3);
      const int csrc = ((lane&7) ^ (lane>>3)) << 3;
      gload_lds16(base + (size_t)(row0 + r)*K + k0 + csrc,
                  &smem[buf][slot][(rlo + i*8)*64]);
    }
  };
  auto frag = [&](const unsigned short* h, int r, int s){
    return *reinterpret_cast<const bf16x8*>(h + r*64 + ((s ^ (r&7)) << 3));
  };

  f32x4 acc[4][4];
  #pragma unroll
  for (int i=0;i<4;++i)
    #pragma unroll
    for (int j=0;j<4;++j) acc[i][j] = (f32x4){0.f,0.f,0.f,0.f};

  // prologue: t0 {A,B} + t1 {A}; vmcnt(4) => t0 landed, A(t1) in flight
  stage(A,  m0, 0, 0, 0);
  stage(Bw, n0, 0, 0, 1);
  if (NT > 1){
    stage(A, m0, 64, 1, 0);
    asm volatile("s_waitcnt vmcnt(4)" ::: "memory");
  } else {
    asm volatile("s_waitcnt vmcnt(0)" ::: "memory");
  }
  __builtin_amdgcn_sched_barrier(0);
  __builtin_amdgcn_s_barrier();

  bf16x8 Ar[4][2];
  bf16x8 Br[2][2];

  auto tile_body = [&](int kt, int cur){
    const int nxt = cur ^ 1;
    const unsigned short* Ah = &smem[cur][0][0];
    const unsigned short* Bh = &smem[cur][1][0];
    const int rbase = wn * 64;

    // ===== P0: A + B-lo reads; stage t+1.B -> nxt; MFMA; P0-end barrier ====
    #pragma unroll
    for (int fm=0;fm<4;++fm)
      #pragma unroll
      for (int kk=0;kk<2;++kk)
        Ar[fm][kk] = frag(Ah, wm*64 + fm*16 + l15, kk*4 + hi);
    #pragma unroll
    for (int nf=0;nf<2;++nf)
      #pragma unroll
      for (int kk=0;kk<2;++kk)
        Br[nf][kk] = frag(Bh, rbase + nf*16 + l15, kk*4 + hi);
    if (kt+1 < NT) stage(Bw, n0, (kt+1)*64, nxt, 1);
    __builtin_amdgcn_sched_barrier(0);
    asm volatile("s_waitcnt lgkmcnt(0)" ::: "memory");
    __builtin_amdgcn_sched_barrier(0);
    __builtin_amdgcn_s_setprio(1);
    #pragma unroll
    for (int fm=0;fm<4;++fm){
      acc[fm][0] = __builtin_amdgcn_mfma_f32_16x16x32_bf16(Ar[fm][0], Br[0][0], acc[fm][0], 0,0,0);
      acc[fm][0] = __builtin_amdgcn_mfma_f32_16x16x32_bf16(Ar[fm][1], Br[0][1], acc[fm][0], 0,0,0);
      acc[fm][1] = __builtin_amdgcn_mfma_f32_16x16x32_bf16(Ar[fm][0], Br[1][0], acc[fm][1], 0,0,0);
      acc[fm][1] = __builtin_amdgcn_mfma_f32_16x16x32_bf16(Ar[fm][1], Br[1][1], acc[fm][1], 0,0,0);
    }
    __builtin_amdgcn_s_setprio(0);
    __builtin_amdgcn_sched_barrier(0);
    __builtin_amdgcn_s_barrier();           // P0-end (required)

    // ===== P1: B-hi reads; stage t+2.A -> cur; MFMA; vmcnt; tile-end =======
    #pragma unroll
    for (int nf=0;nf<2;++nf)
      #pragma unroll
      for (int kk=0;kk<2;++kk)
        Br[nf][kk] = frag(Bh, rbase + 32 + nf*16 + l15, kk*4 + hi);
    if (kt+2 < NT) stage(A, m0, (kt+2)*64, cur, 0);
    __builtin_amdgcn_sched_barrier(0);
    asm volatile("s_waitcnt lgkmcnt(0)" ::: "memory");
    __builtin_amdgcn_sched_barrier(0);
    __builtin_amdgcn_s_setprio(1);
    #pragma unroll
    for (int fm=0;fm<4;++fm){
      acc[fm][2] = __builtin_amdgcn_mfma_f32_16x16x32_bf16(Ar[fm][0], Br[0][0], acc[fm][2], 0,0,0);
      acc[fm][2] = __builtin_amdgcn_mfma_f32_16x16x32_bf16(Ar[fm][1], Br[0][1], acc[fm][2], 0,0,0);
      acc[fm][3] = __builtin_amdgcn_mfma_f32_16x16x32_bf16(Ar[fm][0], Br[1][0], acc[fm][3], 0,0,0);
      acc[fm][3] = __builtin_amdgcn_mfma_f32_16x16x32_bf16(Ar[fm][1], Br[1][1], acc[fm][3], 0,0,0);
    }
    __builtin_amdgcn_s_setprio(0);
    if (kt+2 < NT)      asm volatile("s_waitcnt vmcnt(4)" ::: "memory");
    else if (kt+1 < NT) asm volatile("s_waitcnt vmcnt(0)" ::: "memory");
    __builtin_amdgcn_sched_barrier(0);
    __builtin_amdgcn_s_barrier();           // tile-end (required)
  };

  for (int kt2 = 0; kt2 < NT; kt2 += 2){
    tile_body(kt2,     0);
    tile_body(kt2 + 1, 1);
  }

  #pragma unroll
  for (int fm=0;fm<4;++fm){
    const int row0 = m0 + wm*64 + fm*16 + (hi<<2);
    #pragma unroll
    for (int p=0;p<4;++p){
      const int col = n0 + wn*64 + p*16 + l15;
      f32x4 v = acc[fm][p];
      #pragma unroll
      for (int r=0;r<4;++r) Cf[(size_t)(row0+r)*N + col] = v[r];
    }
  }
}

// ---------------- causal flash attention (v5 + defer-max + balance) --------
// r17: complementary pair remap. Block (x, y) handles pair
// pr = (y&16) ? 15-x : x. Under round-robin dispatch blocks id and id+256
// (same x, y+16) co-reside on a CU -> combined load (32-x)+(17+x) = 49
// tile-units on EVERY CU (was 34..64 -> makespan set by 64).
__global__ __launch_bounds__(256, 2) void attn_kernel(
    const unsigned short* __restrict__ qh,
    const unsigned short* __restrict__ kh,
    const unsigned short* __restrict__ vT,
    unsigned short* __restrict__ ao)
{
  __shared__ __align__(16) unsigned short Ks[2][64*128];   // 32 KB
  __shared__ __align__(16) unsigned short Vs[2][128*64];   // 32 KB
  __shared__ __align__(16) unsigned short Ps[4][16*64];    //  8 KB -> 72 KB

  const int lane = threadIdx.x & 63;
  const int wid  = threadIdx.x >> 6;
  const int hi   = lane >> 4;
  const int l15  = lane & 15;
  const int bh = blockIdx.y;
  const int pr = (bh & 16) ? (15 - blockIdx.x) : blockIdx.x;   // pair 0..15
  const int b_ = bh >> 4, h_ = bh & 15;

  const unsigned short* Qb = qh + (size_t)bh * SEQ * HDIM;
  const unsigned short* Kb = kh + (size_t)bh * SEQ * HDIM;
  const unsigned short* Vb = vT + (size_t)bh * HDIM * SEQ;

  const int qrowf[2] = { pr*64 + wid*16, (31-pr)*64 + wid*16 };

  auto stageKV = [&](int kg, int buf){
    #pragma unroll
    for (int i=0;i<4;++i){
      const int r  = (wid*4+i)*4 + (lane>>4);
      const int cb = ((lane&15)<<4) ^ ((r&7)<<4);
      gload_lds16(Kb + (size_t)(kg*64 + r)*HDIM + (cb>>1), &Ks[buf][0] + (wid*4+i)*512);
    }
    #pragma unroll
    for (int i=0;i<4;++i){
      const int d  = (wid*4+i)*8 + (lane>>3);
      const int cb = ((lane&7)<<4) ^ ((d&7)<<4);
      gload_lds16(Vb + (size_t)d*SEQ + kg*64 + (cb>>1), &Vs[buf][0] + (wid*4+i)*512);
    }
  };

  bf16x8 qf[2][4];
  #pragma unroll
  for (int fi=0; fi<2; ++fi){
    const int qr = qrowf[fi] + l15;
    #pragma unroll
    for (int ks = 0; ks < 4; ++ks)
      qf[fi][ks] = *reinterpret_cast<const bf16x8*>(Qb + (size_t)qr*HDIM + ks*32 + hi*8);
  }

  f32x4 oacc[2][8];
  #pragma unroll
  for (int fi=0;fi<2;++fi)
    #pragma unroll
    for (int t=0;t<8;++t) oacc[fi][t] = (f32x4){0.f,0.f,0.f,0.f};
  float mrun[2][4], lrun[2][4];
  #pragma unroll
  for (int fi=0;fi<2;++fi)
    #pragma unroll
    for (int r=0;r<4;++r){ mrun[fi][r] = -3.0e38f; lrun[fi][r] = 0.f; }

  const int nkt = 32 - pr;            // union of KV ranges for both frags

  stageKV(0, 0);
  __syncthreads();

  for (int kt = 0; kt < nkt; ++kt){
    const int cur = kt & 1;
    if (kt + 1 < nkt) stageKV(kt + 1, cur ^ 1);

    const bool lo_act = (kt <= pr);   // frag 0 active; frag 1 always active

    // ---- S = Q K^T (kf shared across active frags) ----
    f32x4 sacc[2][4];
    #pragma unroll
    for (int fi=0;fi<2;++fi)
      #pragma unroll
      for (int nt=0;nt<4;++nt) sacc[fi][nt] = (f32x4){0.f,0.f,0.f,0.f};
    __builtin_amdgcn_s_setprio(1);
    #pragma unroll
    for (int nt=0;nt<4;++nt){
      const int krow = nt*16 + l15;
      bf16x8 kf[4];
      #pragma unroll
      for (int ks=0;ks<4;++ks){
        const int cb = (ks*64 + (hi<<4)) ^ ((krow&7)<<4);
        kf[ks] = *reinterpret_cast<const bf16x8*>(&Ks[cur][0] + krow*128 + (cb>>1));
      }
      #pragma unroll
      for (int ks=0;ks<4;++ks)
        sacc[1][nt] = __builtin_amdgcn_mfma_f32_16x16x32_bf16(qf[1][ks], kf[ks], sacc[1][nt], 0,0,0);
      if (lo_act){
        #pragma unroll
        for (int ks=0;ks<4;++ks)
          sacc[0][nt] = __builtin_amdgcn_mfma_f32_16x16x32_bf16(qf[0][ks], kf[ks], sacc[0][nt], 0,0,0);
      }
    }
    __builtin_amdgcn_s_setprio(0);

    // ---- per-frag: mask, online softmax (defer-max), P write, PV ----
    char* pb = (char*)&Ps[wid][0];
    #pragma unroll
    for (int fi=0; fi<2; ++fi){
      if (fi == 0 && !lo_act) continue;

      if (kt*64 + 63 > qrowf[fi]){          // mask only on diagonal tiles
        #pragma unroll
        for (int nt=0;nt<4;++nt){
          const int key = kt*64 + nt*16 + l15;
          #pragma unroll
          for (int r=0;r<4;++r){
            const int qr = qrowf[fi] + hi*4 + r;
            if (key > qr) sacc[fi][nt][r] = -1.0e30f;
          }
        }
      }

      // defer-max (T13): skip rescale while max grows by <= 8 (log2 units;
      // P bounded by 2^8=256, bf16-safe).
      float mx[4]; float need = 0.f;
      #pragma unroll
      for (int r=0;r<4;++r){
        float m_ = fmaxf(fmaxf(sacc[fi][0][r], sacc[fi][1][r]),
                         fmaxf(sacc[fi][2][r], sacc[fi][3][r]));
        m_ = rmax16(m_);
        mx[r] = m_;
        need = fmaxf(need, m_ - mrun[fi][r]);
      }
      if (!__all(need <= 8.0f)){
        float fac[4];
        #pragma unroll
        for (int r=0;r<4;++r){
          const float mnew = fmaxf(mrun[fi][r], mx[r]);
          fac[r] = exp2f(mrun[fi][r] - mnew);
          mrun[fi][r] = mnew;
          lrun[fi][r] *= fac[r];
        }
        #pragma unroll
        for (int t=0;t<8;++t)
          #pragma unroll
          for (int r=0;r<4;++r) oacc[fi][t][r] *= fac[r];
      }
      #pragma unroll
      for (int r=0;r<4;++r){
        float ps = 0.f;
        #pragma unroll
        for (int nt=0;nt<4;++nt){
          const float p = exp2f(sacc[fi][nt][r] - mrun[fi][r]);
          sacc[fi][nt][r] = p;
          ps += p;
        }
        ps = rsum16(ps);
        lrun[fi][r] += ps;
      }

      // P (bf16) -> per-wave LDS (16 rows), swizzled
      #pragma unroll
      for (int nt=0;nt<4;++nt){
        const int keyb = (nt*16 + l15) << 1;
        #pragma unroll
        for (int r=0;r<4;++r){
          const int prow = hi*4 + r;
          *(unsigned short*)(pb + prow*128 + (keyb ^ ((prow&7)<<4))) = f2bf(sacc[fi][nt][r]);
        }
      }
      // wave-local LDS RAW: drain ds_writes before pa reads (rule #18)
      asm volatile("s_waitcnt lgkmcnt(0)" ::: "memory");
      __builtin_amdgcn_sched_barrier(0);

      bf16x8 pa[2];
      {
        const int prow = l15;
        #pragma unroll
        for (int ks=0;ks<2;++ks){
          const int pcb = (ks*64 + (hi<<4)) ^ ((prow&7)<<4);
          pa[ks] = *reinterpret_cast<const bf16x8*>(pb + prow*128 + pcb);
        }
      }
      __builtin_amdgcn_s_setprio(1);
      #pragma unroll
      for (int ks=0;ks<2;++ks){
        #pragma unroll
        for (int t=0;t<8;++t){
          const int drow = t*16 + l15;
          const int vcb = (ks*64 + (hi<<4)) ^ ((drow&7)<<4);
          bf16x8 vb = *reinterpret_cast<const bf16x8*>(&Vs[cur][0] + drow*64 + (vcb>>1));
          oacc[fi][t] = __builtin_amdgcn_mfma_f32_16x16x32_bf16(pa[ks], vb, oacc[fi][t], 0,0,0);
        }
      }
      __builtin_amdgcn_s_setprio(0);
    }

    __syncthreads();   // drains next-tile vmcnt + protects K/V buffers
  }

  // ---- epilogue: both frags ----
  #pragma unroll
  for (int fi=0;fi<2;++fi){
    float linv[4];
    #pragma unroll
    for (int r=0;r<4;++r) linv[r] = 1.0f / lrun[fi][r];
    #pragma unroll
    for (int t=0;t<8;++t){
      const int col = h_*HDIM + t*16 + l15;
      #pragma unroll
      for (int r=0;r<4;++r){
        const int s_ = qrowf[fi] + hi*4 + r;
        ao[(size_t)(b_*SEQ + s_)*DMODEL + col] = f2bf(oacc[fi][t][r] * linv[r]);
      }
    }
  }
}

// ---------------- launch ----------------
extern "C" void kernel_launch(void* const* d_in, const int* in_sizes, int n_in,
                              void* d_out, int out_size, void* d_ws, size_t ws_size,
                              hipStream_t stream)
{
  const float* x     = (const float*)d_in[0];
  const float* w_qkv = (const float*)d_in[1];
  const float* w_out = (const float*)d_in[2];
  float* out = (float*)d_out;

  unsigned short* xb    = (unsigned short*)d_ws;                 // 4096x2048
  unsigned short* wqkvb = xb    + (size_t)MTOT*DMODEL;           // 6144x2048
  unsigned short* woutb = wqkvb + (size_t)NQKV*DMODEL;           // 2048x2048
  unsigned short* qhb   = woutb + (size_t)DMODEL*DMODEL;         // (B,H,S,D)
  unsigned short* khb   = qhb   + (size_t)MTOT*DMODEL;           // (B,H,S,D)
  unsigned short* vtb   = khb   + (size_t)MTOT*DMODEL;           // (B,H,D,S)
  unsigned short* aob   = vtb   + (size_t)MTOT*DMODEL;           // 4096x2048
  float2* rtab          = (float2*)(aob + (size_t)MTOT*DMODEL);  // 2048x64 (1 MB)

  hipLaunchKernelGGL(cast3_kernel, dim3(1024), dim3(256), 0, stream,
                     x, xb, MTOT*DMODEL, w_qkv, wqkvb, NQKV*DMODEL, w_out, woutb, DMODEL*DMODEL,
                     rtab);
  hipLaunchKernelGGL((gemm2<0>), dim3(NQKV/256, MTOT/128), dim3(512), 0, stream,
                     xb, wqkvb, (float*)nullptr, qhb, khb, vtb, rtab, MTOT, NQKV, DMODEL);
  hipLaunchKernelGGL(attn_kernel, dim3(16, BATCH*NHEADS), dim3(256), 0, stream, qhb, khb, vtb, aob);
  hipLaunchKernelGGL(gemm_op, dim3(DMODEL/128, MTOT/128), dim3(256), 0, stream,
                     aob, woutb, out, MTOT, DMODEL, DMODEL);
}

// Round 19
// 245.036 us; speedup vs baseline: 1.0780x; 1.0012x over previous
//
#include <hip/hip_runtime.h>
#include <cstdint>
#include <cstddef>

#define NHEADS 16
#define HDIM   128
#define BATCH  2
#define SEQ    2048
#define DMODEL 2048
#define MTOT   (BATCH*SEQ)     // 4096
#define NQKV   (3*DMODEL)      // 6144

typedef __attribute__((ext_vector_type(8))) __bf16 bf16x8;
typedef __attribute__((ext_vector_type(4))) float f32x4;
typedef __attribute__((ext_vector_type(8))) unsigned short ushort8v;

__device__ __forceinline__ unsigned short f2bf(float f){
  __bf16 h = (__bf16)f;
  return __builtin_bit_cast(unsigned short, h);
}
__device__ __forceinline__ float bf2f(unsigned short s){
  return __uint_as_float(((uint32_t)s) << 16);
}
// async global->LDS, 16B per lane; LDS dest is wave-uniform base (+lane*16 by HW)
__device__ __forceinline__ void gload_lds16(const void* src, void* lds_base){
  __builtin_amdgcn_global_load_lds((const __attribute__((address_space(1))) unsigned int*)src,
                                   (__attribute__((address_space(3))) unsigned int*)lds_base,
                                   16, 0, 0);
}

// DPP 16-lane-row rotation butterflies (see round 2)
template<int CTRL>
__device__ __forceinline__ float dppmv(float x){
  return __uint_as_float((unsigned)__builtin_amdgcn_update_dpp(
      0, (int)__float_as_uint(x), CTRL, 0xF, 0xF, true));
}
__device__ __forceinline__ float rmax16(float x){
  x = fmaxf(x, dppmv<0x128>(x));
  x = fmaxf(x, dppmv<0x124>(x));
  x = fmaxf(x, dppmv<0x122>(x));
  x = fmaxf(x, dppmv<0x121>(x));
  return x;
}
__device__ __forceinline__ float rsum16(float x){
  x += dppmv<0x128>(x);
  x += dppmv<0x124>(x);
  x += dppmv<0x122>(x);
  x += dppmv<0x121>(x);
  return x;
}

// ------ fused cast fp32 -> bf16 (3 arrays) + rope cos/sin table build ------
__global__ void cast3_kernel(const float* __restrict__ s0, unsigned short* __restrict__ d0, int n0,
                             const float* __restrict__ s1, unsigned short* __restrict__ d1, int n1,
                             const float* __restrict__ s2, unsigned short* __restrict__ d2, int n2,
                             float2* __restrict__ tab){
  {
    const int i = blockIdx.x*blockDim.x + threadIdx.x;
    if (i < SEQ*64){
      const int j = i & 63, s = i >> 6;
      const float inv = exp2f(-(float)j * (13.287712379549449f/64.f));
      float sn, cs;
      sincosf((float)s * inv, &sn, &cs);
      tab[i] = make_float2(cs, sn);
    }
  }
  const int stride = gridDim.x*blockDim.x*8;
  const int base = (blockIdx.x*blockDim.x + threadIdx.x)*8;
  #pragma unroll 1
  for (int a = 0; a < 3; ++a){
    const float* s = a==0 ? s0 : (a==1 ? s1 : s2);
    unsigned short* d = a==0 ? d0 : (a==1 ? d1 : d2);
    const int n = a==0 ? n0 : (a==1 ? n1 : n2);
    for (int i = base; i < n; i += stride){
      float4 x = *reinterpret_cast<const float4*>(s + i);
      float4 y = *reinterpret_cast<const float4*>(s + i + 4);
      ushort8v o;
      o[0]=f2bf(x.x); o[1]=f2bf(x.y); o[2]=f2bf(x.z); o[3]=f2bf(x.w);
      o[4]=f2bf(y.x); o[5]=f2bf(y.y); o[6]=f2bf(y.z); o[7]=f2bf(y.w);
      *reinterpret_cast<ushort8v*>(d + i) = o;
    }
  }
}

// ---------- 128x256 B^T GEMM, BK=64, 2-phase counted-vmcnt (QKV) -----------
// r16 barrier-minimal: per tile only {P0-end, tile-end} barriers (hazard-
// audited). MODE 0 epilogues: V -> LDS transpose + vT store; Q/K -> fused
// rope via (cos,sin) table + head store.
template<int MODE>
__global__ __launch_bounds__(512, 2) void gemm2(
    const unsigned short* __restrict__ A,
    const unsigned short* __restrict__ Bw,
    float* __restrict__ Cf,
    unsigned short* __restrict__ qo,
    unsigned short* __restrict__ ko,
    unsigned short* __restrict__ vo,
    const float2* __restrict__ rtab,
    int M, int N, int K)
{
  __shared__ __align__(16) unsigned short smem[49152];
  auto lds = reinterpret_cast<unsigned short (*)[3][128*64]>(smem);  // [2][3][8192]

  const int lane = threadIdx.x & 63;
  const int wid  = threadIdx.x >> 6;
  const int wm = wid >> 2, wn = wid & 3;
  const int hi = lane >> 4;
  const int l15 = lane & 15;

  const int nwg = gridDim.x * gridDim.y;
  const int bid = blockIdx.y * gridDim.x + blockIdx.x;
  const int swz = (bid & 7) * (nwg >> 3) + (bid >> 3);
  const int by = swz & 31;
  const int bx = swz >> 5;
  const int m0 = by * 128;
  const int n0 = bx * 256;

  const int NT = K >> 6;

  auto stage = [&](const unsigned short* base, int row0, int k0, int buf, int slot){
    const int rlo = wid << 4;
    #pragma unroll
    for (int i=0;i<2;++i){
      const int r = rlo + i*8 + (lane>>3);
      const int csrc = ((lane&7) ^ (lane>>3)) << 3;   // elems
      gload_lds16(base + (size_t)(row0 + r)*K + k0 + csrc,
                  &lds[buf][slot][(rlo + i*8)*64]);
    }
  };
  auto frag = [&](const unsigned short* h, int r, int s){
    return *reinterpret_cast<const bf16x8*>(h + r*64 + ((s ^ (r&7)) << 3));
  };

  f32x4 acc[4][4];
  #pragma unroll
  for (int i=0;i<4;++i)
    #pragma unroll
    for (int j=0;j<4;++j) acc[i][j] = (f32x4){0.f,0.f,0.f,0.f};

  stage(A,  m0,      0, 0, 0);
  stage(Bw, n0,      0, 0, 1);
  stage(Bw, n0+128,  0, 0, 2);
  if (NT > 1){
    stage(A, m0, 64, 1, 0);
    asm volatile("s_waitcnt vmcnt(2)" ::: "memory");
  } else {
    asm volatile("s_waitcnt vmcnt(0)" ::: "memory");
  }
  __builtin_amdgcn_sched_barrier(0);
  __builtin_amdgcn_s_barrier();

  bf16x8 Ar[4][2];
  bf16x8 Br[2][2];

  auto tile_body = [&](int kt, int cur){
    const int nxt = cur ^ 1;
    const unsigned short* Ah = &lds[cur][0][0];
    const unsigned short* Bh = &lds[cur][1 + (wn>>1)][0];
    const int rbase = (wn & 1) * 64;

    // ===== P0: A + B-lo reads; stage t+1.B -> nxt; MFMA; P0-end barrier ====
    #pragma unroll
    for (int fm=0;fm<4;++fm)
      #pragma unroll
      for (int kk=0;kk<2;++kk)
        Ar[fm][kk] = frag(Ah, wm*64 + fm*16 + l15, kk*4 + hi);
    #pragma unroll
    for (int nf=0;nf<2;++nf)
      #pragma unroll
      for (int kk=0;kk<2;++kk)
        Br[nf][kk] = frag(Bh, rbase + nf*16 + l15, kk*4 + hi);
    if (kt+1 < NT){
      stage(Bw, n0,     (kt+1)*64, nxt, 1);
      stage(Bw, n0+128, (kt+1)*64, nxt, 2);
    }
    __builtin_amdgcn_sched_barrier(0);
    asm volatile("s_waitcnt lgkmcnt(0)" ::: "memory");
    __builtin_amdgcn_sched_barrier(0);
    __builtin_amdgcn_s_setprio(1);
    #pragma unroll
    for (int fm=0;fm<4;++fm){
      acc[fm][0] = __builtin_amdgcn_mfma_f32_16x16x32_bf16(Ar[fm][0], Br[0][0], acc[fm][0], 0,0,0);
      acc[fm][0] = __builtin_amdgcn_mfma_f32_16x16x32_bf16(Ar[fm][1], Br[0][1], acc[fm][0], 0,0,0);
      acc[fm][1] = __builtin_amdgcn_mfma_f32_16x16x32_bf16(Ar[fm][0], Br[1][0], acc[fm][1], 0,0,0);
      acc[fm][1] = __builtin_amdgcn_mfma_f32_16x16x32_bf16(Ar[fm][1], Br[1][1], acc[fm][1], 0,0,0);
    }
    __builtin_amdgcn_s_setprio(0);
    __builtin_amdgcn_sched_barrier(0);
    __builtin_amdgcn_s_barrier();           // P0-end (required)

    // ===== P1: B-hi reads; stage t+2.A -> cur; MFMA; vmcnt; tile-end =======
    #pragma unroll
    for (int nf=0;nf<2;++nf)
      #pragma unroll
      for (int kk=0;kk<2;++kk)
        Br[nf][kk] = frag(Bh, rbase + 32 + nf*16 + l15, kk*4 + hi);
    if (kt+2 < NT) stage(A, m0, (kt+2)*64, cur, 0);
    __builtin_amdgcn_sched_barrier(0);
    asm volatile("s_waitcnt lgkmcnt(0)" ::: "memory");
    __builtin_amdgcn_sched_barrier(0);
    __builtin_amdgcn_s_setprio(1);
    #pragma unroll
    for (int fm=0;fm<4;++fm){
      acc[fm][2] = __builtin_amdgcn_mfma_f32_16x16x32_bf16(Ar[fm][0], Br[0][0], acc[fm][2], 0,0,0);
      acc[fm][2] = __builtin_amdgcn_mfma_f32_16x16x32_bf16(Ar[fm][1], Br[0][1], acc[fm][2], 0,0,0);
      acc[fm][3] = __builtin_amdgcn_mfma_f32_16x16x32_bf16(Ar[fm][0], Br[1][0], acc[fm][3], 0,0,0);
      acc[fm][3] = __builtin_amdgcn_mfma_f32_16x16x32_bf16(Ar[fm][1], Br[1][1], acc[fm][3], 0,0,0);
    }
    __builtin_amdgcn_s_setprio(0);
    if (kt+2 < NT)      asm volatile("s_waitcnt vmcnt(2)" ::: "memory");
    else if (kt+1 < NT) asm volatile("s_waitcnt vmcnt(0)" ::: "memory");
    __builtin_amdgcn_sched_barrier(0);
    __builtin_amdgcn_s_barrier();           // tile-end (required)
  };

  for (int kt2 = 0; kt2 < NT; kt2 += 2){
    tile_body(kt2,     0);
    tile_body(kt2 + 1, 1);
  }

  // ---- epilogue ----
  if (MODE == 0 && (n0 >> 11) == 2){
    // V block: transpose 256(d) x 128(s) tile through LDS, coalesced vT store
    unsigned short* trsp = smem;                  // [256 d][136] ushorts
    #pragma unroll
    for (int fm=0;fm<4;++fm){
      const int srow = wm*64 + fm*16 + hi*4;
      #pragma unroll
      for (int p=0;p<4;++p){
        const int dcol = wn*64 + p*16 + l15;
        f32x4 v = acc[fm][p];
        ushort4 pk;
        pk.x=f2bf(v[0]); pk.y=f2bf(v[1]); pk.z=f2bf(v[2]); pk.w=f2bf(v[3]);
        *reinterpret_cast<ushort4*>(trsp + dcol*136 + srow) = pk;
      }
    }
    __syncthreads();
    const int bb  = m0 >> 11;
    const int ss0 = m0 & 2047;
    const size_t vrow = (size_t)(bb*2048 + (n0 - 4096));
    const int t = threadIdx.x;
    #pragma unroll
    for (int it=0; it<8; ++it){
      const int dl = it*32 + (t>>4);
      const int ch = t & 15;
      ushort8v val = *reinterpret_cast<const ushort8v*>(trsp + dl*136 + ch*8);
      *reinterpret_cast<ushort8v*>(vo + (vrow + dl)*SEQ + ss0 + ch*8) = val;
    }
  } else if (MODE == 0){
    // Q/K block: stage tile row-major in LDS, then fused rope (table) + store
    unsigned short* trsp = smem;                  // [128 rows][264] ushorts
    #pragma unroll
    for (int fm=0;fm<4;++fm){
      const int rowl = wm*64 + fm*16 + hi*4;
      #pragma unroll
      for (int p=0;p<4;++p){
        const int c = wn*64 + p*16 + l15;
        f32x4 v = acc[fm][p];
        #pragma unroll
        for (int r=0;r<4;++r) trsp[(rowl+r)*264 + c] = f2bf(v[r]);
      }
    }
    __syncthreads();
    const bool isq = (n0 >> 11) == 0;
    unsigned short* dst = isq ? qo : ko;
    const float QS = 0.08838834764831845f * 1.4426950408889634f;  // scale*log2e
    const int t = threadIdx.x;                    // 512 threads
    #pragma unroll
    for (int it=0; it<4; ++it){
      const int v = it*512 + t;
      const int rv = v >> 4;
      const int head = (v >> 3) & 1;
      const int jb = (v & 7) * 8;
      ushort8v a = *reinterpret_cast<const ushort8v*>(trsp + rv*264 + head*128 + jb);
      ushort8v b = *reinterpret_cast<const ushort8v*>(trsp + rv*264 + head*128 + 64 + jb);
      const int grow = m0 + rv;
      const int ss = grow & 2047, bb = grow >> 11;
      const int hh = ((n0 >> 7) & 15) + head;
      const float4* tb = reinterpret_cast<const float4*>(rtab + (size_t)ss*64 + jb);
      float csv[8], snv[8];
      #pragma unroll
      for (int q=0;q<4;++q){
        float4 tq = tb[q];
        csv[2*q]   = tq.x; snv[2*q]   = tq.y;
        csv[2*q+1] = tq.z; snv[2*q+1] = tq.w;
      }
      ushort8v o1, o2;
      #pragma unroll
      for (int e=0;e<8;++e){
        float x1 = bf2f(a[e]), x2 = bf2f(b[e]);
        float r1 = x1*csv[e] - x2*snv[e];
        float r2 = x2*csv[e] + x1*snv[e];
        if (isq){ r1 *= QS; r2 *= QS; }
        o1[e] = f2bf(r1); o2[e] = f2bf(r2);
      }
      unsigned short* base = dst + ((size_t)(bb*NHEADS+hh)*SEQ + ss)*HDIM;
      *reinterpret_cast<ushort8v*>(base + jb)      = o1;
      *reinterpret_cast<ushort8v*>(base + 64 + jb) = o2;
    }
  } else {
    #pragma unroll
    for (int fm=0;fm<4;++fm){
      const int row0 = m0 + wm*64 + fm*16 + (hi<<2);
      #pragma unroll
      for (int p=0;p<4;++p){
        const int col = n0 + wn*64 + p*16 + l15;
        f32x4 v = acc[fm][p];
        #pragma unroll
        for (int r=0;r<4;++r) Cf[(size_t)(row0+r)*N + col] = v[r];
      }
    }
  }
}

// ---------- 128x128 B^T GEMM, 4 waves, 64KB LDS -> 2 blocks/CU (out-proj) --
__global__ __launch_bounds__(256, 2) void gemm_op(
    const unsigned short* __restrict__ A,
    const unsigned short* __restrict__ Bw,
    float* __restrict__ Cf,
    int M, int N, int K)
{
  __shared__ __align__(16) unsigned short smem[2][2][128*64];   // 64 KB
  const int lane = threadIdx.x & 63;
  const int wid  = threadIdx.x >> 6;          // 0..3
  const int wm = wid >> 1, wn = wid & 1;      // 2M x 2N, per-wave 64x64
  const int hi = lane >> 4;
  const int l15 = lane & 15;

  const int nwg = gridDim.x * gridDim.y;      // 512
  const int bid = blockIdx.y * gridDim.x + blockIdx.x;
  const int swz = (bid & 7) * (nwg >> 3) + (bid >> 3);
  const int by = swz & 31;
  const int bx = swz >> 5;                    // 0..15
  const int m0 = by * 128;
  const int n0 = bx * 128;

  const int NT = K >> 6;

  auto stage = [&](const unsigned short* base, int row0, int k0, int buf, int slot){
    const int rlo = wid << 5;                 // 32 rows per wave
    #pragma unroll
    for (int i=0;i<4;++i){
      const int r = rlo + i*8 + (lane>>3);
      const int csrc = ((lane&7) ^ (lane>>3)) << 3;
      gload_lds16(base + (size_t)(row0 + r)*K + k0 + csrc,
                  &smem[buf][slot][(rlo + i*8)*64]);
    }
  };
  auto frag = [&](const unsigned short* h, int r, int s){
    return *reinterpret_cast<const bf16x8*>(h + r*64 + ((s ^ (r&7)) << 3));
  };

  f32x4 acc[4][4];
  #pragma unroll
  for (int i=0;i<4;++i)
    #pragma unroll
    for (int j=0;j<4;++j) acc[i][j] = (f32x4){0.f,0.f,0.f,0.f};

  // prologue: t0 {A,B} + t1 {A}; vmcnt(4) => t0 landed, A(t1) in flight
  stage(A,  m0, 0, 0, 0);
  stage(Bw, n0, 0, 0, 1);
  if (NT > 1){
    stage(A, m0, 64, 1, 0);
    asm volatile("s_waitcnt vmcnt(4)" ::: "memory");
  } else {
    asm volatile("s_waitcnt vmcnt(0)" ::: "memory");
  }
  __builtin_amdgcn_sched_barrier(0);
  __builtin_amdgcn_s_barrier();

  bf16x8 Ar[4][2];
  bf16x8 Br[2][2];

  auto tile_body = [&](int kt, int cur){
    const int nxt = cur ^ 1;
    const unsigned short* Ah = &smem[cur][0][0];
    const unsigned short* Bh = &smem[cur][1][0];
    const int rbase = wn * 64;

    // ===== P0: A + B-lo reads; stage t+1.B -> nxt; MFMA; P0-end barrier ====
    #pragma unroll
    for (int fm=0;fm<4;++fm)
      #pragma unroll
      for (int kk=0;kk<2;++kk)
        Ar[fm][kk] = frag(Ah, wm*64 + fm*16 + l15, kk*4 + hi);
    #pragma unroll
    for (int nf=0;nf<2;++nf)
      #pragma unroll
      for (int kk=0;kk<2;++kk)
        Br[nf][kk] = frag(Bh, rbase + nf*16 + l15, kk*4 + hi);
    if (kt+1 < NT) stage(Bw, n0, (kt+1)*64, nxt, 1);
    __builtin_amdgcn_sched_barrier(0);
    asm volatile("s_waitcnt lgkmcnt(0)" ::: "memory");
    __builtin_amdgcn_sched_barrier(0);
    __builtin_amdgcn_s_setprio(1);
    #pragma unroll
    for (int fm=0;fm<4;++fm){
      acc[fm][0] = __builtin_amdgcn_mfma_f32_16x16x32_bf16(Ar[fm][0], Br[0][0], acc[fm][0], 0,0,0);
      acc[fm][0] = __builtin_amdgcn_mfma_f32_16x16x32_bf16(Ar[fm][1], Br[0][1], acc[fm][0], 0,0,0);
      acc[fm][1] = __builtin_amdgcn_mfma_f32_16x16x32_bf16(Ar[fm][0], Br[1][0], acc[fm][1], 0,0,0);
      acc[fm][1] = __builtin_amdgcn_mfma_f32_16x16x32_bf16(Ar[fm][1], Br[1][1], acc[fm][1], 0,0,0);
    }
    __builtin_amdgcn_s_setprio(0);
    __builtin_amdgcn_sched_barrier(0);
    __builtin_amdgcn_s_barrier();           // P0-end (required)

    // ===== P1: B-hi reads; stage t+2.A -> cur; MFMA; vmcnt; tile-end =======
    #pragma unroll
    for (int nf=0;nf<2;++nf)
      #pragma unroll
      for (int kk=0;kk<2;++kk)
        Br[nf][kk] = frag(Bh, rbase + 32 + nf*16 + l15, kk*4 + hi);
    if (kt+2 < NT) stage(A, m0, (kt+2)*64, cur, 0);
    __builtin_amdgcn_sched_barrier(0);
    asm volatile("s_waitcnt lgkmcnt(0)" ::: "memory");
    __builtin_amdgcn_sched_barrier(0);
    __builtin_amdgcn_s_setprio(1);
    #pragma unroll
    for (int fm=0;fm<4;++fm){
      acc[fm][2] = __builtin_amdgcn_mfma_f32_16x16x32_bf16(Ar[fm][0], Br[0][0], acc[fm][2], 0,0,0);
      acc[fm][2] = __builtin_amdgcn_mfma_f32_16x16x32_bf16(Ar[fm][1], Br[0][1], acc[fm][2], 0,0,0);
      acc[fm][3] = __builtin_amdgcn_mfma_f32_16x16x32_bf16(Ar[fm][0], Br[1][0], acc[fm][3], 0,0,0);
      acc[fm][3] = __builtin_amdgcn_mfma_f32_16x16x32_bf16(Ar[fm][1], Br[1][1], acc[fm][3], 0,0,0);
    }
    __builtin_amdgcn_s_setprio(0);
    if (kt+2 < NT)      asm volatile("s_waitcnt vmcnt(4)" ::: "memory");
    else if (kt+1 < NT) asm volatile("s_waitcnt vmcnt(0)" ::: "memory");
    __builtin_amdgcn_sched_barrier(0);
    __builtin_amdgcn_s_barrier();           // tile-end (required)
  };

  for (int kt2 = 0; kt2 < NT; kt2 += 2){
    tile_body(kt2,     0);
    tile_body(kt2 + 1, 1);
  }

  #pragma unroll
  for (int fm=0;fm<4;++fm){
    const int row0 = m0 + wm*64 + fm*16 + (hi<<2);
    #pragma unroll
    for (int p=0;p<4;++p){
      const int col = n0 + wn*64 + p*16 + l15;
      f32x4 v = acc[fm][p];
      #pragma unroll
      for (int r=0;r<4;++r) Cf[(size_t)(row0+r)*N + col] = v[r];
    }
  }
}

// ---------------- causal flash attention (v5 + defer-max + balance) --------
__global__ __launch_bounds__(256, 2) void attn_kernel(
    const unsigned short* __restrict__ qh,
    const unsigned short* __restrict__ kh,
    const unsigned short* __restrict__ vT,
    unsigned short* __restrict__ ao)
{
  __shared__ __align__(16) unsigned short Ks[2][64*128];   // 32 KB
  __shared__ __align__(16) unsigned short Vs[2][128*64];   // 32 KB
  __shared__ __align__(16) unsigned short Ps[4][16*64];    //  8 KB -> 72 KB

  const int lane = threadIdx.x & 63;
  const int wid  = threadIdx.x >> 6;
  const int hi   = lane >> 4;
  const int l15  = lane & 15;
  const int bh = blockIdx.y;
  const int pr = (bh & 16) ? (15 - blockIdx.x) : blockIdx.x;   // pair 0..15
  const int b_ = bh >> 4, h_ = bh & 15;

  const unsigned short* Qb = qh + (size_t)bh * SEQ * HDIM;
  const unsigned short* Kb = kh + (size_t)bh * SEQ * HDIM;
  const unsigned short* Vb = vT + (size_t)bh * HDIM * SEQ;

  const int qrowf[2] = { pr*64 + wid*16, (31-pr)*64 + wid*16 };

  auto stageKV = [&](int kg, int buf){
    #pragma unroll
    for (int i=0;i<4;++i){
      const int r  = (wid*4+i)*4 + (lane>>4);
      const int cb = ((lane&15)<<4) ^ ((r&7)<<4);
      gload_lds16(Kb + (size_t)(kg*64 + r)*HDIM + (cb>>1), &Ks[buf][0] + (wid*4+i)*512);
    }
    #pragma unroll
    for (int i=0;i<4;++i){
      const int d  = (wid*4+i)*8 + (lane>>3);
      const int cb = ((lane&7)<<4) ^ ((d&7)<<4);
      gload_lds16(Vb + (size_t)d*SEQ + kg*64 + (cb>>1), &Vs[buf][0] + (wid*4+i)*512);
    }
  };

  bf16x8 qf[2][4];
  #pragma unroll
  for (int fi=0; fi<2; ++fi){
    const int qr = qrowf[fi] + l15;
    #pragma unroll
    for (int ks = 0; ks < 4; ++ks)
      qf[fi][ks] = *reinterpret_cast<const bf16x8*>(Qb + (size_t)qr*HDIM + ks*32 + hi*8);
  }

  f32x4 oacc[2][8];
  #pragma unroll
  for (int fi=0;fi<2;++fi)
    #pragma unroll
    for (int t=0;t<8;++t) oacc[fi][t] = (f32x4){0.f,0.f,0.f,0.f};
  float mrun[2][4], lrun[2][4];
  #pragma unroll
  for (int fi=0;fi<2;++fi)
    #pragma unroll
    for (int r=0;r<4;++r){ mrun[fi][r] = -3.0e38f; lrun[fi][r] = 0.f; }

  const int nkt = 32 - pr;            // union of KV ranges for both frags

  stageKV(0, 0);
  __syncthreads();

  for (int kt = 0; kt < nkt; ++kt){
    const int cur = kt & 1;
    if (kt + 1 < nkt) stageKV(kt + 1, cur ^ 1);

    const bool lo_act = (kt <= pr);   // frag 0 active; frag 1 always active

    // ---- S = Q K^T (kf shared across active frags) ----
    f32x4 sacc[2][4];
    #pragma unroll
    for (int fi=0;fi<2;++fi)
      #pragma unroll
      for (int nt=0;nt<4;++nt) sacc[fi][nt] = (f32x4){0.f,0.f,0.f,0.f};
    __builtin_amdgcn_s_setprio(1);
    #pragma unroll
    for (int nt=0;nt<4;++nt){
      const int krow = nt*16 + l15;
      bf16x8 kf[4];
      #pragma unroll
      for (int ks=0;ks<4;++ks){
        const int cb = (ks*64 + (hi<<4)) ^ ((krow&7)<<4);
        kf[ks] = *reinterpret_cast<const bf16x8*>(&Ks[cur][0] + krow*128 + (cb>>1));
      }
      #pragma unroll
      for (int ks=0;ks<4;++ks)
        sacc[1][nt] = __builtin_amdgcn_mfma_f32_16x16x32_bf16(qf[1][ks], kf[ks], sacc[1][nt], 0,0,0);
      if (lo_act){
        #pragma unroll
        for (int ks=0;ks<4;++ks)
          sacc[0][nt] = __builtin_amdgcn_mfma_f32_16x16x32_bf16(qf[0][ks], kf[ks], sacc[0][nt], 0,0,0);
      }
    }
    __builtin_amdgcn_s_setprio(0);

    // ---- per-frag: mask, online softmax (defer-max), P write, PV ----
    char* pb = (char*)&Ps[wid][0];
    #pragma unroll
    for (int fi=0; fi<2; ++fi){
      if (fi == 0 && !lo_act) continue;

      if (kt*64 + 63 > qrowf[fi]){          // mask only on diagonal tiles
        #pragma unroll
        for (int nt=0;nt<4;++nt){
          const int key = kt*64 + nt*16 + l15;
          #pragma unroll
          for (int r=0;r<4;++r){
            const int qr = qrowf[fi] + hi*4 + r;
            if (key > qr) sacc[fi][nt][r] = -1.0e30f;
          }
        }
      }

      // defer-max (T13): skip rescale while max grows by <= 8 (log2 units;
      // P bounded by 2^8=256, bf16-safe).
      float mx[4]; float need = 0.f;
      #pragma unroll
      for (int r=0;r<4;++r){
        float m_ = fmaxf(fmaxf(sacc[fi][0][r], sacc[fi][1][r]),
                         fmaxf(sacc[fi][2][r], sacc[fi][3][r]));
        m_ = rmax16(m_);
        mx[r] = m_;
        need = fmaxf(need, m_ - mrun[fi][r]);
      }
      if (!__all(need <= 8.0f)){
        float fac[4];
        #pragma unroll
        for (int r=0;r<4;++r){
          const float mnew = fmaxf(mrun[fi][r], mx[r]);
          fac[r] = exp2f(mrun[fi][r] - mnew);
          mrun[fi][r] = mnew;
          lrun[fi][r] *= fac[r];
        }
        #pragma unroll
        for (int t=0;t<8;++t)
          #pragma unroll
          for (int r=0;r<4;++r) oacc[fi][t][r] *= fac[r];
      }
      #pragma unroll
      for (int r=0;r<4;++r){
        float ps = 0.f;
        #pragma unroll
        for (int nt=0;nt<4;++nt){
          const float p = exp2f(sacc[fi][nt][r] - mrun[fi][r]);
          sacc[fi][nt][r] = p;
          ps += p;
        }
        ps = rsum16(ps);
        lrun[fi][r] += ps;
      }

      // P (bf16) -> per-wave LDS (16 rows), swizzled
      #pragma unroll
      for (int nt=0;nt<4;++nt){
        const int keyb = (nt*16 + l15) << 1;
        #pragma unroll
        for (int r=0;r<4;++r){
          const int prow = hi*4 + r;
          *(unsigned short*)(pb + prow*128 + (keyb ^ ((prow&7)<<4))) = f2bf(sacc[fi][nt][r]);
        }
      }
      // wave-local LDS RAW: drain ds_writes before pa reads (rule #18)
      asm volatile("s_waitcnt lgkmcnt(0)" ::: "memory");
      __builtin_amdgcn_sched_barrier(0);

      bf16x8 pa[2];
      {
        const int prow = l15;
        #pragma unroll
        for (int ks=0;ks<2;++ks){
          const int pcb = (ks*64 + (hi<<4)) ^ ((prow&7)<<4);
          pa[ks] = *reinterpret_cast<const bf16x8*>(pb + prow*128 + pcb);
        }
      }
      __builtin_amdgcn_s_setprio(1);
      #pragma unroll
      for (int ks=0;ks<2;++ks){
        #pragma unroll
        for (int t=0;t<8;++t){
          const int drow = t*16 + l15;
          const int vcb = (ks*64 + (hi<<4)) ^ ((drow&7)<<4);
          bf16x8 vb = *reinterpret_cast<const bf16x8*>(&Vs[cur][0] + drow*64 + (vcb>>1));
          oacc[fi][t] = __builtin_amdgcn_mfma_f32_16x16x32_bf16(pa[ks], vb, oacc[fi][t], 0,0,0);
        }
      }
      __builtin_amdgcn_s_setprio(0);
    }

    __syncthreads();   // drains next-tile vmcnt + protects K/V buffers
  }

  // ---- epilogue: both frags ----
  #pragma unroll
  for (int fi=0;fi<2;++fi){
    float linv[4];
    #pragma unroll
    for (int r=0;r<4;++r) linv[r] = 1.0f / lrun[fi][r];
    #pragma unroll
    for (int t=0;t<8;++t){
      const int col = h_*HDIM + t*16 + l15;
      #pragma unroll
      for (int r=0;r<4;++r){
        const int s_ = qrowf[fi] + hi*4 + r;
        ao[(size_t)(b_*SEQ + s_)*DMODEL + col] = f2bf(oacc[fi][t][r] * linv[r]);
      }
    }
  }
}

// ---------------- launch ----------------
extern "C" void kernel_launch(void* const* d_in, const int* in_sizes, int n_in,
                              void* d_out, int out_size, void* d_ws, size_t ws_size,
                              hipStream_t stream)
{
  const float* x     = (const float*)d_in[0];
  const float* w_qkv = (const float*)d_in[1];
  const float* w_out = (const float*)d_in[2];
  float* out = (float*)d_out;

  unsigned short* xb    = (unsigned short*)d_ws;                 // 4096x2048
  unsigned short* wqkvb = xb    + (size_t)MTOT*DMODEL;           // 6144x2048
  unsigned short* woutb = wqkvb + (size_t)NQKV*DMODEL;           // 2048x2048
  unsigned short* qhb   = woutb + (size_t)DMODEL*DMODEL;         // (B,H,S,D)
  unsigned short* khb   = qhb   + (size_t)MTOT*DMODEL;           // (B,H,S,D)
  unsigned short* vtb   = khb   + (size_t)MTOT*DMODEL;           // (B,H,D,S)
  unsigned short* aob   = vtb   + (size_t)MTOT*DMODEL;           // 4096x2048
  float2* rtab          = (float2*)(aob + (size_t)MTOT*DMODEL);  // 2048x64 (1 MB)

  hipLaunchKernelGGL(cast3_kernel, dim3(1024), dim3(256), 0, stream,
                     x, xb, MTOT*DMODEL, w_qkv, wqkvb, NQKV*DMODEL, w_out, woutb, DMODEL*DMODEL,
                     rtab);
  hipLaunchKernelGGL((gemm2<0>), dim3(NQKV/256, MTOT/128), dim3(512), 0, stream,
                     xb, wqkvb, (float*)nullptr, qhb, khb, vtb, rtab, MTOT, NQKV, DMODEL);
  hipLaunchKernelGGL(attn_kernel, dim3(16, BATCH*NHEADS), dim3(256), 0, stream, qhb, khb, vtb, aob);
  hipLaunchKernelGGL(gemm_op, dim3(DMODEL/128, MTOT/128), dim3(256), 0, stream,
                     aob, woutb, out, MTOT, DMODEL, DMODEL);
}